// Round 5
// baseline (475.640 us; speedup 1.0000x reference)
//
#include <hip/hip_runtime.h>
#include <hip/hip_bf16.h>

#define N_NODES 30000
#define M_PAD   30016     // 469*64
#define N_EDGES 480000
#define N_GRAPH 64
#define L_TOK   20
#define D_EMB   32
#define S_SCAL  64
#define TOT     224      // S + 5*D, = 7*32
#define H1      4
#define C1      128
#define F1      512      // H1*C1
#define F2      128
#define E_TOT   (N_EDGES + N_NODES)

typedef __attribute__((ext_vector_type(8))) short bf16x8;
typedef __attribute__((ext_vector_type(4))) float f32x4;

__device__ __forceinline__ unsigned short f2b(float f) {
    unsigned u = __float_as_uint(f);
    u += 0x7FFFu + ((u >> 16) & 1u);
    return (unsigned short)(u >> 16);
}
__device__ __forceinline__ float b2f(unsigned short h) {
    return __uint_as_float(((unsigned)h) << 16);
}
__device__ __forceinline__ float blo(unsigned u) { return __uint_as_float(u << 16); }
__device__ __forceinline__ float bhi(unsigned u) { return __uint_as_float(u & 0xFFFF0000u); }

// ---------------- CSR build ----------------
__global__ void init_deg(int* deg) {
    int i = blockIdx.x * blockDim.x + threadIdx.x;
    if (i < N_NODES) deg[i] = 1;   // self loop
}

__global__ void add_deg(const int* __restrict__ ei, int* deg) {
    int e = blockIdx.x * blockDim.x + threadIdx.x;
    if (e < N_EDGES) atomicAdd(&deg[ei[N_EDGES + e]], 1);
}

#define SCAN_PER 30
__global__ void scan_deg(const int* __restrict__ deg, int* __restrict__ rowptr,
                         int* __restrict__ cursor) {
    int t = threadIdx.x, lane = t & 63, wid = t >> 6;   // 16 waves
    int base = t * SCAN_PER;
    int v[SCAN_PER];
    int lsum = 0;
    #pragma unroll
    for (int i = 0; i < SCAN_PER; ++i) {
        int ii = base + i;
        int d = (ii < N_NODES) ? deg[ii] : 0;
        v[i] = lsum;
        lsum += d;
    }
    int incl = lsum;
    #pragma unroll
    for (int off = 1; off < 64; off <<= 1) {
        int u = __shfl_up(incl, off);
        if (lane >= off) incl += u;
    }
    __shared__ int wsum[16], woff[16];
    if (lane == 63) wsum[wid] = incl;
    __syncthreads();
    if (t == 0) {
        int run = 0;
        #pragma unroll
        for (int w = 0; w < 16; ++w) { woff[w] = run; run += wsum[w]; }
        rowptr[N_NODES] = run;
    }
    __syncthreads();
    int texcl = woff[wid] + (incl - lsum);
    #pragma unroll
    for (int i = 0; i < SCAN_PER; ++i) {
        int ii = base + i;
        if (ii < N_NODES) { int p = texcl + v[i]; rowptr[ii] = p; cursor[ii] = p; }
    }
}

__global__ void scatter_edges(const int* __restrict__ ei, int* cursor, int* csr_src) {
    int e = blockIdx.x * blockDim.x + threadIdx.x;
    if (e < N_EDGES) {
        int src = ei[e], dst = ei[N_EDGES + e];
        int pos = atomicAdd(&cursor[dst], 1);
        csr_src[pos] = src;
    } else if (e < E_TOT) {
        int n = e - N_EDGES;
        int pos = atomicAdd(&cursor[n], 1);
        csr_src[pos] = n;
    }
}

// ---------------- weight transpose+cast ----------------
__global__ void transpose_cast(const float* __restrict__ W, unsigned short* __restrict__ WT,
                               int K, int N) {
    int idx = blockIdx.x * blockDim.x + threadIdx.x;
    if (idx < K * N) {
        int n = idx / K, k = idx - n * K;
        WT[idx] = f2b(W[(size_t)k * N + n]);
    }
}

// ---------------- features + layernorm (bf16 out), wave-per-node ----------------
__global__ void feat_ln(const float* __restrict__ xs,
                        const int* __restrict__ xo, const int* __restrict__ xsrc,
                        const int* __restrict__ xsink, const int* __restrict__ xstr,
                        const int* __restrict__ xpay,
                        const float* __restrict__ eo, const float* __restrict__ es,
                        const float* __restrict__ ek, const float* __restrict__ eg,
                        const float* __restrict__ ep,
                        const float* __restrict__ lns, const float* __restrict__ lnb,
                        unsigned short* __restrict__ x0) {
    int node = blockIdx.x * 4 + (threadIdx.x >> 6);
    if (node >= N_NODES) return;
    int lane = threadIdx.x & 63;
    int c = lane * 4;
    float f0 = 0.f, f1 = 0.f, f2 = 0.f, f3 = 0.f;
    if (lane < 16) {
        float4 v = *reinterpret_cast<const float4*>(&xs[(size_t)node * S_SCAL + c]);
        f0 = v.x; f1 = v.y; f2 = v.z; f3 = v.w;
    } else if (lane < 56) {
        int t = c - S_SCAL;
        int ti = t >> 5, dim = t & 31;
        const int* idx; const float* emb;
        switch (ti) {
            case 0: idx = xo;   emb = eo; break;
            case 1: idx = xsrc; emb = es; break;
            case 2: idx = xsink;emb = ek; break;
            case 3: idx = xstr; emb = eg; break;
            default:idx = xpay; emb = ep; break;
        }
        float a0 = 0.f, a1 = 0.f, a2 = 0.f, a3 = 0.f, cnt = 0.f;
        #pragma unroll
        for (int l = 0; l < L_TOK; ++l) {
            int id = idx[node * L_TOK + l];
            if (id != 0) {
                float4 e = *reinterpret_cast<const float4*>(&emb[id * D_EMB + dim]);
                a0 += e.x; a1 += e.y; a2 += e.z; a3 += e.w; cnt += 1.f;
            }
        }
        float r = 1.f / (cnt + 1e-9f);
        f0 = a0 * r; f1 = a1 * r; f2 = a2 * r; f3 = a3 * r;
    }
    float s = f0 + f1 + f2 + f3;
    float q = f0 * f0 + f1 * f1 + f2 * f2 + f3 * f3;
    #pragma unroll
    for (int off = 32; off; off >>= 1) {
        s += __shfl_xor(s, off);
        q += __shfl_xor(q, off);
    }
    float mu = s * (1.f / (float)TOT);
    float var = q * (1.f / (float)TOT) - mu * mu;
    float rs = rsqrtf(var + 1e-5f);
    if (lane < 56) {
        float4 sc = *reinterpret_cast<const float4*>(&lns[c]);
        float4 bi = *reinterpret_cast<const float4*>(&lnb[c]);
        ushort4 o;
        o.x = f2b((f0 - mu) * rs * sc.x + bi.x);
        o.y = f2b((f1 - mu) * rs * sc.y + bi.y);
        o.z = f2b((f2 - mu) * rs * sc.z + bi.z);
        o.w = f2b((f3 - mu) * rs * sc.w + bi.w);
        *reinterpret_cast<ushort4*>(&x0[(size_t)node * TOT + c]) = o;
    }
}

// ---------------- bf16 MFMA GEMM ----------------
__global__ void gemm_bf16(const unsigned short* __restrict__ A,
                          const unsigned short* __restrict__ BT,
                          unsigned short* __restrict__ C, int M, int N, int K) {
    __shared__ unsigned short As[64][40];
    __shared__ unsigned short Bs[64][40];
    int tid = threadIdx.x;
    int wave = tid >> 6, lane = tid & 63;
    int l15 = lane & 15, kb = lane >> 4;
    int bm = blockIdx.x * 64, bn = blockIdx.y * 64;
    f32x4 acc[4] = {};
    int row_ld = tid >> 2, seg = tid & 3;
    for (int k0 = 0; k0 < K; k0 += 32) {
        {
            const uint4 v = *reinterpret_cast<const uint4*>(&A[(size_t)(bm + row_ld) * K + k0 + seg * 8]);
            *reinterpret_cast<uint4*>(&As[row_ld][seg * 8]) = v;
        }
        {
            const uint4 v = *reinterpret_cast<const uint4*>(&BT[(size_t)(bn + row_ld) * K + k0 + seg * 8]);
            *reinterpret_cast<uint4*>(&Bs[row_ld][seg * 8]) = v;
        }
        __syncthreads();
        bf16x8 af = *reinterpret_cast<const bf16x8*>(&As[wave * 16 + l15][kb * 8]);
        #pragma unroll
        for (int t = 0; t < 4; ++t) {
            bf16x8 bfr = *reinterpret_cast<const bf16x8*>(&Bs[t * 16 + l15][kb * 8]);
            acc[t] = __builtin_amdgcn_mfma_f32_16x16x32_bf16(af, bfr, acc[t], 0, 0, 0);
        }
        __syncthreads();
    }
    #pragma unroll
    for (int t = 0; t < 4; ++t) {
        #pragma unroll
        for (int r = 0; r < 4; ++r) {
            int row = bm + wave * 16 + kb * 4 + r;
            if (row < M)
                C[(size_t)row * N + bn + t * 16 + l15] = f2b(acc[t][r]);
        }
    }
}

// ---------------- attention prep (wave per node, 4 nodes/block) ----------------
__global__ void att_prep1(const unsigned short* __restrict__ h1, const float* __restrict__ asrc,
                          const float* __restrict__ adst, float* __restrict__ s1,
                          float* __restrict__ d1) {
    int node = blockIdx.x * 4 + (threadIdx.x >> 6);
    if (node >= N_NODES) return;
    int lane = threadIdx.x & 63;
    const uint4* h1u4 = (const uint4*)h1;          // row = 64 uint4
    uint4 v = h1u4[(size_t)node * 64 + lane];
    int c = lane * 8, head = lane >> 4;
    float h[8] = { blo(v.x), bhi(v.x), blo(v.y), bhi(v.y),
                   blo(v.z), bhi(v.z), blo(v.w), bhi(v.w) };
    float4 a0 = *reinterpret_cast<const float4*>(&asrc[c]);
    float4 a1 = *reinterpret_cast<const float4*>(&asrc[c + 4]);
    float4 d0 = *reinterpret_cast<const float4*>(&adst[c]);
    float4 d4 = *reinterpret_cast<const float4*>(&adst[c + 4]);
    float sv = h[0]*a0.x + h[1]*a0.y + h[2]*a0.z + h[3]*a0.w
             + h[4]*a1.x + h[5]*a1.y + h[6]*a1.z + h[7]*a1.w;
    float dv = h[0]*d0.x + h[1]*d0.y + h[2]*d0.z + h[3]*d0.w
             + h[4]*d4.x + h[5]*d4.y + h[6]*d4.z + h[7]*d4.w;
    #pragma unroll
    for (int off = 8; off; off >>= 1) { sv += __shfl_xor(sv, off); dv += __shfl_xor(dv, off); }
    if ((lane & 15) == 0) {
        s1[node * H1 + head] = sv;
        d1[node * H1 + head] = dv;
    }
}

__global__ void att_prep2(const unsigned short* __restrict__ h2, const float* __restrict__ asrc,
                          const float* __restrict__ adst, float* __restrict__ s2,
                          float* __restrict__ d2) {
    int node = blockIdx.x * 4 + (threadIdx.x >> 6);
    if (node >= N_NODES) return;
    int lane = threadIdx.x & 63;
    const unsigned* h2u = (const unsigned*)h2;     // row = 64 uints
    unsigned v = h2u[(size_t)node * 64 + lane];
    float h0 = blo(v), h1v = bhi(v);
    float sv = h0 * asrc[2 * lane] + h1v * asrc[2 * lane + 1];
    float dv = h0 * adst[2 * lane] + h1v * adst[2 * lane + 1];
    #pragma unroll
    for (int off = 32; off; off >>= 1) { sv += __shfl_xor(sv, off); dv += __shfl_xor(dv, off); }
    if (lane == 0) { s2[node] = sv; d2[node] = dv; }
}

// ---------------- GAT layer 1: softmax + aggregate + bias + elu ----------------
__global__ void gat1_aggregate(const unsigned short* __restrict__ h1, const float* __restrict__ s1,
                               const float* __restrict__ d1, const int* __restrict__ rowptr,
                               const int* __restrict__ csr, const float* __restrict__ b1,
                               unsigned short* __restrict__ x1) {
    int n = blockIdx.x, tid = threadIdx.x;    // 256 threads
    int wave = tid >> 6, lane = tid & 63;
    int half = tid >> 7, t = tid & 127, head = t >> 5;   // half IS wave-uniform
    int r0 = rowptr[n], deg = rowptr[n + 1] - r0;
    __shared__ float alpha_sh[H1][64];
    __shared__ int src_sh[64];
    __shared__ float d_n[H1];
    __shared__ float4 red[128];
    if (tid < H1) d_n[tid] = d1[n * H1 + tid];
    __syncthreads();
    float dnw = d_n[wave];
    const uint2* h1u2 = (const uint2*)h1;     // row = 128 uint2
    float4 acc = make_float4(0.f, 0.f, 0.f, 0.f);

    if (deg <= 64) {
        // ---- fast path: single-pass softmax in registers ----
        float e = -1e30f;
        if (lane < deg) {
            int src = csr[r0 + lane];
            if (wave == 0) src_sh[lane] = src;
            float ev = s1[src * H1 + wave] + dnw;
            e = (ev >= 0.f) ? ev : 0.2f * ev;
        }
        float m = e;
        #pragma unroll
        for (int off = 32; off; off >>= 1) m = fmaxf(m, __shfl_xor(m, off));
        float ex = (lane < deg) ? __expf(e - m) : 0.f;
        float den = ex;
        #pragma unroll
        for (int off = 32; off; off >>= 1) den += __shfl_xor(den, off);
        alpha_sh[wave][lane] = ex / den;
        __syncthreads();
        for (int i = half; i < deg; i += 2) {
            int src = __builtin_amdgcn_readfirstlane(src_sh[i]);   // i wave-uniform here
            float a = alpha_sh[head][i];
            uint2 v = h1u2[(size_t)src * 128 + t];
            acc.x += a * blo(v.x); acc.y += a * bhi(v.x);
            acc.z += a * blo(v.y); acc.w += a * bhi(v.y);
        }
    } else {
        // ---- generic chunked path ----
        float m = -1e30f;
        for (int i = lane; i < deg; i += 64) {
            int src = csr[r0 + i];
            float e = s1[src * H1 + wave] + dnw;
            e = (e >= 0.f) ? e : 0.2f * e;
            m = fmaxf(m, e);
        }
        #pragma unroll
        for (int off = 32; off; off >>= 1) m = fmaxf(m, __shfl_xor(m, off));
        float den = 0.f;
        for (int i = lane; i < deg; i += 64) {
            int src = csr[r0 + i];
            float e = s1[src * H1 + wave] + dnw;
            e = (e >= 0.f) ? e : 0.2f * e;
            den += __expf(e - m);
        }
        #pragma unroll
        for (int off = 32; off; off >>= 1) den += __shfl_xor(den, off);
        float invw = 1.f / den;
        for (int c0 = 0; c0 < deg; c0 += 64) {
            __syncthreads();
            int i = c0 + lane;
            if (i < deg) {
                int src = csr[r0 + i];
                if (wave == 0) src_sh[lane] = src;
                float e = s1[src * H1 + wave] + dnw;
                e = (e >= 0.f) ? e : 0.2f * e;
                alpha_sh[wave][lane] = __expf(e - m) * invw;
            }
            __syncthreads();
            int cnt = min(64, deg - c0);
            for (int i2 = half; i2 < cnt; i2 += 2) {
                int src = __builtin_amdgcn_readfirstlane(src_sh[i2]);
                float a = alpha_sh[head][i2];
                uint2 v = h1u2[(size_t)src * 128 + t];
                acc.x += a * blo(v.x); acc.y += a * bhi(v.x);
                acc.z += a * blo(v.y); acc.w += a * bhi(v.y);
            }
        }
    }
    // combine halves + epilogue
    if (half == 1) red[t] = acc;
    __syncthreads();
    if (half == 0) {
        float4 o = red[t];
        float4 bv = *reinterpret_cast<const float4*>(&b1[4 * t]);
        float v0 = acc.x + o.x + bv.x; v0 = (v0 > 0.f) ? v0 : expm1f(v0);
        float v1 = acc.y + o.y + bv.y; v1 = (v1 > 0.f) ? v1 : expm1f(v1);
        float v2 = acc.z + o.z + bv.z; v2 = (v2 > 0.f) ? v2 : expm1f(v2);
        float v3 = acc.w + o.w + bv.w; v3 = (v3 > 0.f) ? v3 : expm1f(v3);
        uint2 pk;
        pk.x = (unsigned)f2b(v0) | ((unsigned)f2b(v1) << 16);
        pk.y = (unsigned)f2b(v2) | ((unsigned)f2b(v3) << 16);
        ((uint2*)x1)[(size_t)n * 128 + t] = pk;
    }
}

// ---------------- GAT layer 2 + elu + graph max-pool ----------------
__device__ __forceinline__ unsigned int f2ord(float f) {
    unsigned int b = __float_as_uint(f);
    return (b & 0x80000000u) ? ~b : (b | 0x80000000u);
}

__global__ void pool_init(unsigned int* pool) {
    int i = blockIdx.x * blockDim.x + threadIdx.x;
    if (i < N_GRAPH * F2) pool[i] = 0x007FFFFFu;   // f2ord(-inf)
}

__global__ void gat2_pool(const unsigned short* __restrict__ h2, const float* __restrict__ s2,
                          const float* __restrict__ d2, const int* __restrict__ rowptr,
                          const int* __restrict__ csr, const float* __restrict__ b2,
                          const int* __restrict__ batch, unsigned int* __restrict__ pool) {
    int n = blockIdx.x, tid = threadIdx.x;   // 128 threads
    int wid = tid >> 6, lane = tid & 63;
    int g = tid >> 5, t = tid & 31;          // g NOT wave-uniform: no readfirstlane below
    int r0 = rowptr[n], deg = rowptr[n + 1] - r0;
    __shared__ float alpha_sh[128];
    __shared__ int src_sh[128];
    __shared__ float rA[2], rB[2];
    __shared__ float4 r2[4][32];
    float dn = d2[n];
    const uint2* h2u2 = (const uint2*)h2;    // row = 32 uint2
    float4 acc = make_float4(0.f, 0.f, 0.f, 0.f);

    if (deg <= 128) {
        // ---- fast path ----
        float e = -1e30f;
        if (tid < deg) {
            int src = csr[r0 + tid];
            src_sh[tid] = src;
            float ev = s2[src] + dn;
            e = (ev >= 0.f) ? ev : 0.2f * ev;
        }
        float m = e;
        #pragma unroll
        for (int off = 32; off; off >>= 1) m = fmaxf(m, __shfl_xor(m, off));
        if (lane == 0) rA[wid] = m;
        __syncthreads();
        m = fmaxf(rA[0], rA[1]);
        float ex = (tid < deg) ? __expf(e - m) : 0.f;
        float den = ex;
        #pragma unroll
        for (int off = 32; off; off >>= 1) den += __shfl_xor(den, off);
        if (lane == 0) rB[wid] = den;
        __syncthreads();
        den = rB[0] + rB[1];
        alpha_sh[tid] = ex / den;
        __syncthreads();
        for (int i = g; i < deg; i += 4) {
            int src = src_sh[i];             // LDS broadcast per 32-lane group
            float a = alpha_sh[i];
            uint2 v = h2u2[(size_t)src * 32 + t];
            acc.x += a * blo(v.x); acc.y += a * bhi(v.x);
            acc.z += a * blo(v.y); acc.w += a * bhi(v.y);
        }
    } else {
        // ---- generic chunked path ----
        float m = -1e30f;
        for (int i = tid; i < deg; i += 128) {
            float e = s2[csr[r0 + i]] + dn; e = (e >= 0.f) ? e : 0.2f * e;
            m = fmaxf(m, e);
        }
        #pragma unroll
        for (int off = 32; off; off >>= 1) m = fmaxf(m, __shfl_xor(m, off));
        if (lane == 0) rA[wid] = m;
        __syncthreads();
        m = fmaxf(rA[0], rA[1]);
        float den = 0.f;
        for (int i = tid; i < deg; i += 128) {
            float e = s2[csr[r0 + i]] + dn; e = (e >= 0.f) ? e : 0.2f * e;
            den += __expf(e - m);
        }
        #pragma unroll
        for (int off = 32; off; off >>= 1) den += __shfl_xor(den, off);
        if (lane == 0) rB[wid] = den;
        __syncthreads();
        den = rB[0] + rB[1];
        float inv = 1.f / den;
        for (int c0 = 0; c0 < deg; c0 += 128) {
            __syncthreads();
            int i = c0 + tid;
            if (i < deg) {
                int src = csr[r0 + i];
                src_sh[tid] = src;
                float e = s2[src] + dn; e = (e >= 0.f) ? e : 0.2f * e;
                alpha_sh[tid] = __expf(e - m) * inv;
            }
            __syncthreads();
            int cnt = min(128, deg - c0);
            for (int i2 = g; i2 < cnt; i2 += 4) {
                int src = src_sh[i2];
                float a = alpha_sh[i2];
                uint2 v = h2u2[(size_t)src * 32 + t];
                acc.x += a * blo(v.x); acc.y += a * bhi(v.x);
                acc.z += a * blo(v.y); acc.w += a * bhi(v.y);
            }
        }
    }
    r2[g][t] = acc;
    __syncthreads();
    if (g == 0) {
        float4 p1 = r2[1][t], p2 = r2[2][t], p3 = r2[3][t];
        float4 bv = *reinterpret_cast<const float4*>(&b2[4 * t]);
        float v0 = acc.x + p1.x + p2.x + p3.x + bv.x; v0 = (v0 > 0.f) ? v0 : expm1f(v0);
        float v1 = acc.y + p1.y + p2.y + p3.y + bv.y; v1 = (v1 > 0.f) ? v1 : expm1f(v1);
        float v2 = acc.z + p1.z + p2.z + p3.z + bv.z; v2 = (v2 > 0.f) ? v2 : expm1f(v2);
        float v3 = acc.w + p1.w + p2.w + p3.w + bv.w; v3 = (v3 > 0.f) ? v3 : expm1f(v3);
        int base = batch[n] * F2 + 4 * t;
        atomicMax(&pool[base + 0], f2ord(v0));
        atomicMax(&pool[base + 1], f2ord(v1));
        atomicMax(&pool[base + 2], f2ord(v2));
        atomicMax(&pool[base + 3], f2ord(v3));
    }
}

__global__ void pool_finalize(const unsigned int* __restrict__ pool, float* __restrict__ out) {
    int i = blockIdx.x * blockDim.x + threadIdx.x;
    if (i < N_GRAPH * F2) {
        unsigned int k = pool[i];
        unsigned int b = (k & 0x80000000u) ? (k ^ 0x80000000u) : ~k;
        out[i] = __uint_as_float(b);
    }
}

// ---------------- launcher ----------------
extern "C" void kernel_launch(void* const* d_in, const int* in_sizes, int n_in,
                              void* d_out, int out_size, void* d_ws, size_t ws_size,
                              hipStream_t stream) {
    const float* x_scalar = (const float*)d_in[0];
    const int*   x_opcode = (const int*)d_in[1];
    const int*   x_source = (const int*)d_in[2];
    const int*   x_sink   = (const int*)d_in[3];
    const int*   x_string = (const int*)d_in[4];
    const int*   x_payload= (const int*)d_in[5];
    const int*   edge_idx = (const int*)d_in[6];
    const int*   batch    = (const int*)d_in[7];
    const float* emb_op   = (const float*)d_in[8];
    const float* emb_src  = (const float*)d_in[9];
    const float* emb_snk  = (const float*)d_in[10];
    const float* emb_str  = (const float*)d_in[11];
    const float* emb_pay  = (const float*)d_in[12];
    const float* ln_scale = (const float*)d_in[13];
    const float* ln_bias  = (const float*)d_in[14];
    const float* W1       = (const float*)d_in[15];
    const float* att_src1 = (const float*)d_in[16];
    const float* att_dst1 = (const float*)d_in[17];
    const float* b1       = (const float*)d_in[18];
    const float* W2       = (const float*)d_in[19];
    const float* att_src2 = (const float*)d_in[20];
    const float* att_dst2 = (const float*)d_in[21];
    const float* b2       = (const float*)d_in[22];
    float* out = (float*)d_out;

    // workspace layout
    unsigned short* x0  = (unsigned short*)d_ws;               // M_PAD*224 bf16
    unsigned short* h1  = x0 + (size_t)M_PAD * TOT;            // M_PAD*512
    unsigned short* x1  = h1 + (size_t)M_PAD * F1;             // M_PAD*512
    unsigned short* h2  = x1 + (size_t)M_PAD * F1;             // M_PAD*128
    unsigned short* W1T = h2 + (size_t)M_PAD * F2;             // 512*224
    unsigned short* W2T = W1T + (size_t)F1 * TOT;              // 128*512
    float* s1 = (float*)(W2T + (size_t)F2 * F1);               // N*4
    float* d1 = s1 + (size_t)N_NODES * H1;
    float* s2 = d1 + (size_t)N_NODES * H1;                     // N
    float* d2 = s2 + N_NODES;
    int* rowptr = (int*)(d2 + N_NODES);                        // N+1
    int* cursor = rowptr + (N_NODES + 1);                      // N+1
    int* csr    = cursor + (N_NODES + 1);                      // E_TOT
    unsigned int* pool = (unsigned int*)(csr + E_TOT);         // G*128

    // CSR build
    init_deg<<<(N_NODES + 255) / 256, 256, 0, stream>>>(cursor);
    add_deg<<<(N_EDGES + 255) / 256, 256, 0, stream>>>(edge_idx, cursor);
    scan_deg<<<1, 1024, 0, stream>>>(cursor, rowptr, cursor);
    scatter_edges<<<(E_TOT + 255) / 256, 256, 0, stream>>>(edge_idx, cursor, csr);

    // weight transposes
    transpose_cast<<<(TOT * F1 + 255) / 256, 256, 0, stream>>>(W1, W1T, TOT, F1);
    transpose_cast<<<(F1 * F2 + 255) / 256, 256, 0, stream>>>(W2, W2T, F1, F2);

    // features + LN
    feat_ln<<<(N_NODES + 3) / 4, 256, 0, stream>>>(x_scalar, x_opcode, x_source, x_sink,
                                                   x_string, x_payload, emb_op, emb_src,
                                                   emb_snk, emb_str, emb_pay, ln_scale,
                                                   ln_bias, x0);

    // layer 1
    dim3 g1(M_PAD / 64, F1 / 64);
    gemm_bf16<<<g1, 256, 0, stream>>>(x0, W1T, h1, N_NODES, F1, TOT);
    att_prep1<<<(N_NODES + 3) / 4, 256, 0, stream>>>(h1, att_src1, att_dst1, s1, d1);
    gat1_aggregate<<<N_NODES, 256, 0, stream>>>(h1, s1, d1, rowptr, csr, b1, x1);

    // layer 2
    dim3 g2(M_PAD / 64, F2 / 64);
    gemm_bf16<<<g2, 256, 0, stream>>>(x1, W2T, h2, N_NODES, F2, F1);
    att_prep2<<<(N_NODES + 3) / 4, 256, 0, stream>>>(h2, att_src2, att_dst2, s2, d2);

    pool_init<<<(N_GRAPH * F2 + 255) / 256, 256, 0, stream>>>(pool);
    gat2_pool<<<N_NODES, 128, 0, stream>>>(h2, s2, d2, rowptr, csr, b2, batch, pool);
    pool_finalize<<<(N_GRAPH * F2 + 255) / 256, 256, 0, stream>>>(pool, out);
}

// Round 6
// 367.585 us; speedup vs baseline: 1.2940x; 1.2940x over previous
//
#include <hip/hip_runtime.h>
#include <hip/hip_bf16.h>
#include <math.h>

#define N_NODES 30000
#define M_PAD   30016     // 469*64
#define N_EDGES 480000
#define N_GRAPH 64
#define L_TOK   20
#define D_EMB   32
#define S_SCAL  64
#define TOT     224      // S + 5*D, = 7*32
#define H1      4
#define C1      128
#define F1      512      // H1*C1
#define F2      128
#define E_TOT   (N_EDGES + N_NODES)

typedef __attribute__((ext_vector_type(8))) short bf16x8;
typedef __attribute__((ext_vector_type(4))) float f32x4;

__device__ __forceinline__ unsigned short f2b(float f) {
    unsigned u = __float_as_uint(f);
    u += 0x7FFFu + ((u >> 16) & 1u);
    return (unsigned short)(u >> 16);
}
__device__ __forceinline__ float b2f(unsigned short h) {
    return __uint_as_float(((unsigned)h) << 16);
}
__device__ __forceinline__ float blo(unsigned u) { return __uint_as_float(u << 16); }
__device__ __forceinline__ float bhi(unsigned u) { return __uint_as_float(u & 0xFFFF0000u); }

// ---------------- CSR build ----------------
__global__ void init_deg(int* deg) {
    int i = blockIdx.x * blockDim.x + threadIdx.x;
    if (i < N_NODES) deg[i] = 1;   // self loop
}

__global__ void add_deg(const int* __restrict__ ei, int* deg) {
    int e = blockIdx.x * blockDim.x + threadIdx.x;
    if (e < N_EDGES) atomicAdd(&deg[ei[N_EDGES + e]], 1);
}

#define SCAN_PER 30
__global__ void scan_deg(const int* __restrict__ deg, int* __restrict__ rowptr,
                         int* __restrict__ cursor) {
    int t = threadIdx.x, lane = t & 63, wid = t >> 6;   // 16 waves
    int base = t * SCAN_PER;
    int v[SCAN_PER];
    int lsum = 0;
    #pragma unroll
    for (int i = 0; i < SCAN_PER; ++i) {
        int ii = base + i;
        int d = (ii < N_NODES) ? deg[ii] : 0;
        v[i] = lsum;
        lsum += d;
    }
    int incl = lsum;
    #pragma unroll
    for (int off = 1; off < 64; off <<= 1) {
        int u = __shfl_up(incl, off);
        if (lane >= off) incl += u;
    }
    __shared__ int wsum[16], woff[16];
    if (lane == 63) wsum[wid] = incl;
    __syncthreads();
    if (t == 0) {
        int run = 0;
        #pragma unroll
        for (int w = 0; w < 16; ++w) { woff[w] = run; run += wsum[w]; }
        rowptr[N_NODES] = run;
    }
    __syncthreads();
    int texcl = woff[wid] + (incl - lsum);
    #pragma unroll
    for (int i = 0; i < SCAN_PER; ++i) {
        int ii = base + i;
        if (ii < N_NODES) { int p = texcl + v[i]; rowptr[ii] = p; cursor[ii] = p; }
    }
}

__global__ void scatter_edges(const int* __restrict__ ei, int* cursor, int* csr_src) {
    int e = blockIdx.x * blockDim.x + threadIdx.x;
    if (e < N_EDGES) {
        int src = ei[e], dst = ei[N_EDGES + e];
        int pos = atomicAdd(&cursor[dst], 1);
        csr_src[pos] = src;
    } else if (e < E_TOT) {
        int n = e - N_EDGES;
        int pos = atomicAdd(&cursor[n], 1);
        csr_src[pos] = n;
    }
}

// ---------------- weight transpose+cast ----------------
__global__ void transpose_cast(const float* __restrict__ W, unsigned short* __restrict__ WT,
                               int K, int N) {
    int idx = blockIdx.x * blockDim.x + threadIdx.x;
    if (idx < K * N) {
        int n = idx / K, k = idx - n * K;
        WT[idx] = f2b(W[(size_t)k * N + n]);
    }
}

// ---------------- features + layernorm (bf16 out), wave-per-node ----------------
__global__ void feat_ln(const float* __restrict__ xs,
                        const int* __restrict__ xo, const int* __restrict__ xsrc,
                        const int* __restrict__ xsink, const int* __restrict__ xstr,
                        const int* __restrict__ xpay,
                        const float* __restrict__ eo, const float* __restrict__ es,
                        const float* __restrict__ ek, const float* __restrict__ eg,
                        const float* __restrict__ ep,
                        const float* __restrict__ lns, const float* __restrict__ lnb,
                        unsigned short* __restrict__ x0) {
    int node = blockIdx.x * 4 + (threadIdx.x >> 6);
    if (node >= N_NODES) return;
    int lane = threadIdx.x & 63;
    int c = lane * 4;
    float f0 = 0.f, f1 = 0.f, f2 = 0.f, f3 = 0.f;
    if (lane < 16) {
        float4 v = *reinterpret_cast<const float4*>(&xs[(size_t)node * S_SCAL + c]);
        f0 = v.x; f1 = v.y; f2 = v.z; f3 = v.w;
    } else if (lane < 56) {
        int t = c - S_SCAL;
        int ti = t >> 5, dim = t & 31;
        const int* idx; const float* emb;
        switch (ti) {
            case 0: idx = xo;   emb = eo; break;
            case 1: idx = xsrc; emb = es; break;
            case 2: idx = xsink;emb = ek; break;
            case 3: idx = xstr; emb = eg; break;
            default:idx = xpay; emb = ep; break;
        }
        float a0 = 0.f, a1 = 0.f, a2 = 0.f, a3 = 0.f, cnt = 0.f;
        #pragma unroll
        for (int l = 0; l < L_TOK; ++l) {
            int id = idx[node * L_TOK + l];
            if (id != 0) {
                float4 e = *reinterpret_cast<const float4*>(&emb[id * D_EMB + dim]);
                a0 += e.x; a1 += e.y; a2 += e.z; a3 += e.w; cnt += 1.f;
            }
        }
        float r = 1.f / (cnt + 1e-9f);
        f0 = a0 * r; f1 = a1 * r; f2 = a2 * r; f3 = a3 * r;
    }
    float s = f0 + f1 + f2 + f3;
    float q = f0 * f0 + f1 * f1 + f2 * f2 + f3 * f3;
    #pragma unroll
    for (int off = 32; off; off >>= 1) {
        s += __shfl_xor(s, off);
        q += __shfl_xor(q, off);
    }
    float mu = s * (1.f / (float)TOT);
    float var = q * (1.f / (float)TOT) - mu * mu;
    float rs = rsqrtf(var + 1e-5f);
    if (lane < 56) {
        float4 sc = *reinterpret_cast<const float4*>(&lns[c]);
        float4 bi = *reinterpret_cast<const float4*>(&lnb[c]);
        ushort4 o;
        o.x = f2b((f0 - mu) * rs * sc.x + bi.x);
        o.y = f2b((f1 - mu) * rs * sc.y + bi.y);
        o.z = f2b((f2 - mu) * rs * sc.z + bi.z);
        o.w = f2b((f3 - mu) * rs * sc.w + bi.w);
        *reinterpret_cast<ushort4*>(&x0[(size_t)node * TOT + c]) = o;
    }
}

// ---------------- bf16 MFMA GEMM ----------------
__global__ void gemm_bf16(const unsigned short* __restrict__ A,
                          const unsigned short* __restrict__ BT,
                          unsigned short* __restrict__ C, int M, int N, int K) {
    __shared__ unsigned short As[64][40];
    __shared__ unsigned short Bs[64][40];
    int tid = threadIdx.x;
    int wave = tid >> 6, lane = tid & 63;
    int l15 = lane & 15, kb = lane >> 4;
    int bm = blockIdx.x * 64, bn = blockIdx.y * 64;
    f32x4 acc[4] = {};
    int row_ld = tid >> 2, seg = tid & 3;
    for (int k0 = 0; k0 < K; k0 += 32) {
        {
            const uint4 v = *reinterpret_cast<const uint4*>(&A[(size_t)(bm + row_ld) * K + k0 + seg * 8]);
            *reinterpret_cast<uint4*>(&As[row_ld][seg * 8]) = v;
        }
        {
            const uint4 v = *reinterpret_cast<const uint4*>(&BT[(size_t)(bn + row_ld) * K + k0 + seg * 8]);
            *reinterpret_cast<uint4*>(&Bs[row_ld][seg * 8]) = v;
        }
        __syncthreads();
        bf16x8 af = *reinterpret_cast<const bf16x8*>(&As[wave * 16 + l15][kb * 8]);
        #pragma unroll
        for (int t = 0; t < 4; ++t) {
            bf16x8 bfr = *reinterpret_cast<const bf16x8*>(&Bs[t * 16 + l15][kb * 8]);
            acc[t] = __builtin_amdgcn_mfma_f32_16x16x32_bf16(af, bfr, acc[t], 0, 0, 0);
        }
        __syncthreads();
    }
    #pragma unroll
    for (int t = 0; t < 4; ++t) {
        #pragma unroll
        for (int r = 0; r < 4; ++r) {
            int row = bm + wave * 16 + kb * 4 + r;
            if (row < M)
                C[(size_t)row * N + bn + t * 16 + l15] = f2b(acc[t][r]);
        }
    }
}

// ---------------- attention prep (wave per node, 4 nodes/block) ----------------
__global__ void att_prep1(const unsigned short* __restrict__ h1, const float* __restrict__ asrc,
                          const float* __restrict__ adst, float* __restrict__ s1,
                          float* __restrict__ d1) {
    int node = blockIdx.x * 4 + (threadIdx.x >> 6);
    if (node >= N_NODES) return;
    int lane = threadIdx.x & 63;
    const uint4* h1u4 = (const uint4*)h1;          // row = 64 uint4
    uint4 v = h1u4[(size_t)node * 64 + lane];
    int c = lane * 8, head = lane >> 4;
    float h[8] = { blo(v.x), bhi(v.x), blo(v.y), bhi(v.y),
                   blo(v.z), bhi(v.z), blo(v.w), bhi(v.w) };
    float4 a0 = *reinterpret_cast<const float4*>(&asrc[c]);
    float4 a1 = *reinterpret_cast<const float4*>(&asrc[c + 4]);
    float4 d0 = *reinterpret_cast<const float4*>(&adst[c]);
    float4 d4 = *reinterpret_cast<const float4*>(&adst[c + 4]);
    float sv = h[0]*a0.x + h[1]*a0.y + h[2]*a0.z + h[3]*a0.w
             + h[4]*a1.x + h[5]*a1.y + h[6]*a1.z + h[7]*a1.w;
    float dv = h[0]*d0.x + h[1]*d0.y + h[2]*d0.z + h[3]*d0.w
             + h[4]*d4.x + h[5]*d4.y + h[6]*d4.z + h[7]*d4.w;
    #pragma unroll
    for (int off = 8; off; off >>= 1) { sv += __shfl_xor(sv, off); dv += __shfl_xor(dv, off); }
    if ((lane & 15) == 0) {
        s1[node * H1 + head] = sv;
        d1[node * H1 + head] = dv;
    }
}

__global__ void att_prep2(const unsigned short* __restrict__ h2, const float* __restrict__ asrc,
                          const float* __restrict__ adst, float* __restrict__ s2,
                          float* __restrict__ d2) {
    int node = blockIdx.x * 4 + (threadIdx.x >> 6);
    if (node >= N_NODES) return;
    int lane = threadIdx.x & 63;
    const unsigned* h2u = (const unsigned*)h2;     // row = 64 uints
    unsigned v = h2u[(size_t)node * 64 + lane];
    float h0 = blo(v), h1v = bhi(v);
    float sv = h0 * asrc[2 * lane] + h1v * asrc[2 * lane + 1];
    float dv = h0 * adst[2 * lane] + h1v * adst[2 * lane + 1];
    #pragma unroll
    for (int off = 32; off; off >>= 1) { sv += __shfl_xor(sv, off); dv += __shfl_xor(dv, off); }
    if (lane == 0) { s2[node] = sv; d2[node] = dv; }
}

// ---------------- GAT layer 1: softmax + aggregate + bias + elu ----------------
__global__ void gat1_aggregate(const unsigned short* __restrict__ h1, const float* __restrict__ s1,
                               const float* __restrict__ d1, const int* __restrict__ rowptr,
                               const int* __restrict__ csr, const float* __restrict__ b1,
                               unsigned short* __restrict__ x1) {
    int n = blockIdx.x, tid = threadIdx.x;    // 256 threads
    int wave = tid >> 6, lane = tid & 63;
    int half = tid >> 7, t = tid & 127, head = t >> 5;   // half IS wave-uniform
    int r0 = rowptr[n], deg = rowptr[n + 1] - r0;
    __shared__ float alpha_sh[H1][64];
    __shared__ int src_sh[64];
    __shared__ float d_n[H1];
    __shared__ float4 red[128];
    if (tid < H1) d_n[tid] = d1[n * H1 + tid];
    __syncthreads();
    float dnw = d_n[wave];
    const uint2* h1u2 = (const uint2*)h1;     // row = 128 uint2
    float4 acc = make_float4(0.f, 0.f, 0.f, 0.f);

    if (deg <= 64) {
        // ---- fast path: single-pass softmax in registers ----
        float e = -1e30f;
        if (lane < deg) {
            int src = csr[r0 + lane];
            if (wave == 0) src_sh[lane] = src;
            float ev = s1[src * H1 + wave] + dnw;
            e = (ev >= 0.f) ? ev : 0.2f * ev;
        }
        float m = e;
        #pragma unroll
        for (int off = 32; off; off >>= 1) m = fmaxf(m, __shfl_xor(m, off));
        float ex = (lane < deg) ? __expf(e - m) : 0.f;
        float den = ex;
        #pragma unroll
        for (int off = 32; off; off >>= 1) den += __shfl_xor(den, off);
        alpha_sh[wave][lane] = ex / den;
        __syncthreads();
        for (int i = half; i < deg; i += 2) {
            int src = __builtin_amdgcn_readfirstlane(src_sh[i]);   // i wave-uniform here
            float a = alpha_sh[head][i];
            uint2 v = h1u2[(size_t)src * 128 + t];
            acc.x += a * blo(v.x); acc.y += a * bhi(v.x);
            acc.z += a * blo(v.y); acc.w += a * bhi(v.y);
        }
    } else {
        // ---- generic chunked path ----
        float m = -1e30f;
        for (int i = lane; i < deg; i += 64) {
            int src = csr[r0 + i];
            float e = s1[src * H1 + wave] + dnw;
            e = (e >= 0.f) ? e : 0.2f * e;
            m = fmaxf(m, e);
        }
        #pragma unroll
        for (int off = 32; off; off >>= 1) m = fmaxf(m, __shfl_xor(m, off));
        float den = 0.f;
        for (int i = lane; i < deg; i += 64) {
            int src = csr[r0 + i];
            float e = s1[src * H1 + wave] + dnw;
            e = (e >= 0.f) ? e : 0.2f * e;
            den += __expf(e - m);
        }
        #pragma unroll
        for (int off = 32; off; off >>= 1) den += __shfl_xor(den, off);
        float invw = 1.f / den;
        for (int c0 = 0; c0 < deg; c0 += 64) {
            __syncthreads();
            int i = c0 + lane;
            if (i < deg) {
                int src = csr[r0 + i];
                if (wave == 0) src_sh[lane] = src;
                float e = s1[src * H1 + wave] + dnw;
                e = (e >= 0.f) ? e : 0.2f * e;
                alpha_sh[wave][lane] = __expf(e - m) * invw;
            }
            __syncthreads();
            int cnt = min(64, deg - c0);
            for (int i2 = half; i2 < cnt; i2 += 2) {
                int src = __builtin_amdgcn_readfirstlane(src_sh[i2]);
                float a = alpha_sh[head][i2];
                uint2 v = h1u2[(size_t)src * 128 + t];
                acc.x += a * blo(v.x); acc.y += a * bhi(v.x);
                acc.z += a * blo(v.y); acc.w += a * bhi(v.y);
            }
        }
    }
    // combine halves + epilogue
    if (half == 1) red[t] = acc;
    __syncthreads();
    if (half == 0) {
        float4 o = red[t];
        float4 bv = *reinterpret_cast<const float4*>(&b1[4 * t]);
        float v0 = acc.x + o.x + bv.x; v0 = (v0 > 0.f) ? v0 : expm1f(v0);
        float v1 = acc.y + o.y + bv.y; v1 = (v1 > 0.f) ? v1 : expm1f(v1);
        float v2 = acc.z + o.z + bv.z; v2 = (v2 > 0.f) ? v2 : expm1f(v2);
        float v3 = acc.w + o.w + bv.w; v3 = (v3 > 0.f) ? v3 : expm1f(v3);
        uint2 pk;
        pk.x = (unsigned)f2b(v0) | ((unsigned)f2b(v1) << 16);
        pk.y = (unsigned)f2b(v2) | ((unsigned)f2b(v3) << 16);
        ((uint2*)x1)[(size_t)n * 128 + t] = pk;
    }
}

// ---------------- GAT layer 2 per-node output (no atomics) ----------------
__global__ void gat2_node(const unsigned short* __restrict__ h2, const float* __restrict__ s2,
                          const float* __restrict__ d2, const int* __restrict__ rowptr,
                          const int* __restrict__ csr, const float* __restrict__ b2,
                          float* __restrict__ h2act) {
    int n = blockIdx.x, tid = threadIdx.x;   // 128 threads
    int wid = tid >> 6, lane = tid & 63;
    int g = tid >> 5, t = tid & 31;          // g NOT wave-uniform: no readfirstlane below
    int r0 = rowptr[n], deg = rowptr[n + 1] - r0;
    __shared__ float alpha_sh[128];
    __shared__ int src_sh[128];
    __shared__ float rA[2], rB[2];
    __shared__ float4 r2[4][32];
    float dn = d2[n];
    const uint2* h2u2 = (const uint2*)h2;    // row = 32 uint2
    float4 acc = make_float4(0.f, 0.f, 0.f, 0.f);

    if (deg <= 128) {
        // ---- fast path ----
        float e = -1e30f;
        if (tid < deg) {
            int src = csr[r0 + tid];
            src_sh[tid] = src;
            float ev = s2[src] + dn;
            e = (ev >= 0.f) ? ev : 0.2f * ev;
        }
        float m = e;
        #pragma unroll
        for (int off = 32; off; off >>= 1) m = fmaxf(m, __shfl_xor(m, off));
        if (lane == 0) rA[wid] = m;
        __syncthreads();
        m = fmaxf(rA[0], rA[1]);
        float ex = (tid < deg) ? __expf(e - m) : 0.f;
        float den = ex;
        #pragma unroll
        for (int off = 32; off; off >>= 1) den += __shfl_xor(den, off);
        if (lane == 0) rB[wid] = den;
        __syncthreads();
        den = rB[0] + rB[1];
        alpha_sh[tid] = ex / den;
        __syncthreads();
        for (int i = g; i < deg; i += 4) {
            int src = src_sh[i];             // LDS broadcast per 32-lane group
            float a = alpha_sh[i];
            uint2 v = h2u2[(size_t)src * 32 + t];
            acc.x += a * blo(v.x); acc.y += a * bhi(v.x);
            acc.z += a * blo(v.y); acc.w += a * bhi(v.y);
        }
    } else {
        // ---- generic chunked path ----
        float m = -1e30f;
        for (int i = tid; i < deg; i += 128) {
            float e = s2[csr[r0 + i]] + dn; e = (e >= 0.f) ? e : 0.2f * e;
            m = fmaxf(m, e);
        }
        #pragma unroll
        for (int off = 32; off; off >>= 1) m = fmaxf(m, __shfl_xor(m, off));
        if (lane == 0) rA[wid] = m;
        __syncthreads();
        m = fmaxf(rA[0], rA[1]);
        float den = 0.f;
        for (int i = tid; i < deg; i += 128) {
            float e = s2[csr[r0 + i]] + dn; e = (e >= 0.f) ? e : 0.2f * e;
            den += __expf(e - m);
        }
        #pragma unroll
        for (int off = 32; off; off >>= 1) den += __shfl_xor(den, off);
        if (lane == 0) rB[wid] = den;
        __syncthreads();
        den = rB[0] + rB[1];
        float inv = 1.f / den;
        for (int c0 = 0; c0 < deg; c0 += 128) {
            __syncthreads();
            int i = c0 + tid;
            if (i < deg) {
                int src = csr[r0 + i];
                src_sh[tid] = src;
                float e = s2[src] + dn; e = (e >= 0.f) ? e : 0.2f * e;
                alpha_sh[tid] = __expf(e - m) * inv;
            }
            __syncthreads();
            int cnt = min(128, deg - c0);
            for (int i2 = g; i2 < cnt; i2 += 4) {
                int src = src_sh[i2];
                float a = alpha_sh[i2];
                uint2 v = h2u2[(size_t)src * 32 + t];
                acc.x += a * blo(v.x); acc.y += a * bhi(v.x);
                acc.z += a * blo(v.y); acc.w += a * bhi(v.y);
            }
        }
    }
    r2[g][t] = acc;
    __syncthreads();
    if (g == 0) {
        float4 p1 = r2[1][t], p2 = r2[2][t], p3 = r2[3][t];
        float4 bv = *reinterpret_cast<const float4*>(&b2[4 * t]);
        float v0 = acc.x + p1.x + p2.x + p3.x + bv.x; v0 = (v0 > 0.f) ? v0 : expm1f(v0);
        float v1 = acc.y + p1.y + p2.y + p3.y + bv.y; v1 = (v1 > 0.f) ? v1 : expm1f(v1);
        float v2 = acc.z + p1.z + p2.z + p3.z + bv.z; v2 = (v2 > 0.f) ? v2 : expm1f(v2);
        float v3 = acc.w + p1.w + p2.w + p3.w + bv.w; v3 = (v3 > 0.f) ? v3 : expm1f(v3);
        *reinterpret_cast<float4*>(&h2act[(size_t)n * F2 + 4 * t]) = make_float4(v0, v1, v2, v3);
    }
}

// ---------------- per-graph max-pool (batch sorted -> contiguous ranges) ----------------
__global__ void graph_pool(const float* __restrict__ h2act, const int* __restrict__ batch,
                           float* __restrict__ out) {
    int gph = blockIdx.x;                     // 64 blocks
    int tid = threadIdx.x;                    // 256: noff = tid>>7, ch = tid&127
    __shared__ int se[2];
    __shared__ float red[128];
    if (tid < 2) {
        int target = gph + tid;               // first index with batch[i] >= target
        int lo = 0, hi = N_NODES;
        while (lo < hi) { int mid = (lo + hi) >> 1; if (batch[mid] < target) lo = mid + 1; else hi = mid; }
        se[tid] = lo;
    }
    __syncthreads();
    int start = se[0], end = se[1];
    int ch = tid & 127, noff = tid >> 7;
    float m = -INFINITY;
    for (int i = start + noff; i < end; i += 2)
        m = fmaxf(m, h2act[(size_t)i * F2 + ch]);
    if (noff == 1) red[ch] = m;
    __syncthreads();
    if (noff == 0) out[gph * F2 + ch] = fmaxf(m, red[ch]);
}

// ---------------- launcher ----------------
extern "C" void kernel_launch(void* const* d_in, const int* in_sizes, int n_in,
                              void* d_out, int out_size, void* d_ws, size_t ws_size,
                              hipStream_t stream) {
    const float* x_scalar = (const float*)d_in[0];
    const int*   x_opcode = (const int*)d_in[1];
    const int*   x_source = (const int*)d_in[2];
    const int*   x_sink   = (const int*)d_in[3];
    const int*   x_string = (const int*)d_in[4];
    const int*   x_payload= (const int*)d_in[5];
    const int*   edge_idx = (const int*)d_in[6];
    const int*   batch    = (const int*)d_in[7];
    const float* emb_op   = (const float*)d_in[8];
    const float* emb_src  = (const float*)d_in[9];
    const float* emb_snk  = (const float*)d_in[10];
    const float* emb_str  = (const float*)d_in[11];
    const float* emb_pay  = (const float*)d_in[12];
    const float* ln_scale = (const float*)d_in[13];
    const float* ln_bias  = (const float*)d_in[14];
    const float* W1       = (const float*)d_in[15];
    const float* att_src1 = (const float*)d_in[16];
    const float* att_dst1 = (const float*)d_in[17];
    const float* b1       = (const float*)d_in[18];
    const float* W2       = (const float*)d_in[19];
    const float* att_src2 = (const float*)d_in[20];
    const float* att_dst2 = (const float*)d_in[21];
    const float* b2       = (const float*)d_in[22];
    float* out = (float*)d_out;

    // workspace layout
    unsigned short* x0  = (unsigned short*)d_ws;               // M_PAD*224 bf16
    unsigned short* h1  = x0 + (size_t)M_PAD * TOT;            // M_PAD*512
    unsigned short* x1  = h1 + (size_t)M_PAD * F1;             // M_PAD*512
    unsigned short* h2  = x1 + (size_t)M_PAD * F1;             // M_PAD*128
    unsigned short* W1T = h2 + (size_t)M_PAD * F2;             // 512*224
    unsigned short* W2T = W1T + (size_t)F1 * TOT;              // 128*512
    float* s1 = (float*)(W2T + (size_t)F2 * F1);               // N*4
    float* d1 = s1 + (size_t)N_NODES * H1;
    float* s2 = d1 + (size_t)N_NODES * H1;                     // N
    float* d2 = s2 + N_NODES;
    int* rowptr = (int*)(d2 + N_NODES);                        // N+1
    int* cursor = rowptr + (N_NODES + 1);                      // N+1
    int* csr    = cursor + (N_NODES + 1);                      // E_TOT
    float* h2act = (float*)x1;                                 // alias: x1 dead after gemm2

    // CSR build
    init_deg<<<(N_NODES + 255) / 256, 256, 0, stream>>>(cursor);
    add_deg<<<(N_EDGES + 255) / 256, 256, 0, stream>>>(edge_idx, cursor);
    scan_deg<<<1, 1024, 0, stream>>>(cursor, rowptr, cursor);
    scatter_edges<<<(E_TOT + 255) / 256, 256, 0, stream>>>(edge_idx, cursor, csr);

    // weight transposes
    transpose_cast<<<(TOT * F1 + 255) / 256, 256, 0, stream>>>(W1, W1T, TOT, F1);
    transpose_cast<<<(F1 * F2 + 255) / 256, 256, 0, stream>>>(W2, W2T, F1, F2);

    // features + LN
    feat_ln<<<(N_NODES + 3) / 4, 256, 0, stream>>>(x_scalar, x_opcode, x_source, x_sink,
                                                   x_string, x_payload, emb_op, emb_src,
                                                   emb_snk, emb_str, emb_pay, ln_scale,
                                                   ln_bias, x0);

    // layer 1
    dim3 g1(M_PAD / 64, F1 / 64);
    gemm_bf16<<<g1, 256, 0, stream>>>(x0, W1T, h1, N_NODES, F1, TOT);
    att_prep1<<<(N_NODES + 3) / 4, 256, 0, stream>>>(h1, att_src1, att_dst1, s1, d1);
    gat1_aggregate<<<N_NODES, 256, 0, stream>>>(h1, s1, d1, rowptr, csr, b1, x1);

    // layer 2
    dim3 g2(M_PAD / 64, F2 / 64);
    gemm_bf16<<<g2, 256, 0, stream>>>(x1, W2T, h2, N_NODES, F2, F1);
    att_prep2<<<(N_NODES + 3) / 4, 256, 0, stream>>>(h2, att_src2, att_dst2, s2, d2);

    gat2_node<<<N_NODES, 128, 0, stream>>>(h2, s2, d2, rowptr, csr, b2, h2act);
    graph_pool<<<N_GRAPH, 256, 0, stream>>>(h2act, batch, out);
}

// Round 7
// 343.532 us; speedup vs baseline: 1.3846x; 1.0700x over previous
//
#include <hip/hip_runtime.h>
#include <hip/hip_bf16.h>
#include <math.h>

#define N_NODES 30000
#define M_PAD   30016     // 469*64
#define N_EDGES 480000
#define N_GRAPH 64
#define L_TOK   20
#define D_EMB   32
#define S_SCAL  64
#define TOT     224      // S + 5*D, = 7*32
#define H1      4
#define C1      128
#define F1      512      // H1*C1
#define F2      128
#define E_TOT   (N_EDGES + N_NODES)

typedef __attribute__((ext_vector_type(8))) short bf16x8;
typedef __attribute__((ext_vector_type(4))) float f32x4;

__device__ __forceinline__ unsigned short f2b(float f) {
    unsigned u = __float_as_uint(f);
    u += 0x7FFFu + ((u >> 16) & 1u);
    return (unsigned short)(u >> 16);
}
__device__ __forceinline__ float b2f(unsigned short h) {
    return __uint_as_float(((unsigned)h) << 16);
}
__device__ __forceinline__ float blo(unsigned u) { return __uint_as_float(u << 16); }
__device__ __forceinline__ float bhi(unsigned u) { return __uint_as_float(u & 0xFFFF0000u); }

// ---------------- CSR build ----------------
__global__ void init_deg(int* deg) {
    int i = blockIdx.x * blockDim.x + threadIdx.x;
    if (i < N_NODES) deg[i] = 1;   // self loop
}

__global__ void add_deg(const int* __restrict__ ei, int* deg) {
    int e = blockIdx.x * blockDim.x + threadIdx.x;
    if (e < N_EDGES) atomicAdd(&deg[ei[N_EDGES + e]], 1);
}

#define SCAN_PER 30
__global__ void scan_deg(const int* __restrict__ deg, int* __restrict__ rowptr,
                         int* __restrict__ cursor) {
    int t = threadIdx.x, lane = t & 63, wid = t >> 6;   // 16 waves
    int base = t * SCAN_PER;
    int v[SCAN_PER];
    int lsum = 0;
    #pragma unroll
    for (int i = 0; i < SCAN_PER; ++i) {
        int ii = base + i;
        int d = (ii < N_NODES) ? deg[ii] : 0;
        v[i] = lsum;
        lsum += d;
    }
    int incl = lsum;
    #pragma unroll
    for (int off = 1; off < 64; off <<= 1) {
        int u = __shfl_up(incl, off);
        if (lane >= off) incl += u;
    }
    __shared__ int wsum[16], woff[16];
    if (lane == 63) wsum[wid] = incl;
    __syncthreads();
    if (t == 0) {
        int run = 0;
        #pragma unroll
        for (int w = 0; w < 16; ++w) { woff[w] = run; run += wsum[w]; }
        rowptr[N_NODES] = run;
    }
    __syncthreads();
    int texcl = woff[wid] + (incl - lsum);
    #pragma unroll
    for (int i = 0; i < SCAN_PER; ++i) {
        int ii = base + i;
        if (ii < N_NODES) { int p = texcl + v[i]; rowptr[ii] = p; cursor[ii] = p; }
    }
}

__global__ void scatter_edges(const int* __restrict__ ei, int* cursor, int* csr_src) {
    int e = blockIdx.x * blockDim.x + threadIdx.x;
    if (e < N_EDGES) {
        int src = ei[e], dst = ei[N_EDGES + e];
        int pos = atomicAdd(&cursor[dst], 1);
        csr_src[pos] = src;
    } else if (e < E_TOT) {
        int n = e - N_EDGES;
        int pos = atomicAdd(&cursor[n], 1);
        csr_src[pos] = n;
    }
}

// ---------------- weight transpose+cast ----------------
__global__ void transpose_cast(const float* __restrict__ W, unsigned short* __restrict__ WT,
                               int K, int N) {
    int idx = blockIdx.x * blockDim.x + threadIdx.x;
    if (idx < K * N) {
        int n = idx / K, k = idx - n * K;
        WT[idx] = f2b(W[(size_t)k * N + n]);
    }
}

// ---------------- features + layernorm (bf16 out), wave-per-node ----------------
__global__ void feat_ln(const float* __restrict__ xs,
                        const int* __restrict__ xo, const int* __restrict__ xsrc,
                        const int* __restrict__ xsink, const int* __restrict__ xstr,
                        const int* __restrict__ xpay,
                        const float* __restrict__ eo, const float* __restrict__ es,
                        const float* __restrict__ ek, const float* __restrict__ eg,
                        const float* __restrict__ ep,
                        const float* __restrict__ lns, const float* __restrict__ lnb,
                        unsigned short* __restrict__ x0) {
    int node = blockIdx.x * 4 + (threadIdx.x >> 6);
    if (node >= N_NODES) return;
    int lane = threadIdx.x & 63;
    int c = lane * 4;
    float f0 = 0.f, f1 = 0.f, f2 = 0.f, f3 = 0.f;
    if (lane < 16) {
        float4 v = *reinterpret_cast<const float4*>(&xs[(size_t)node * S_SCAL + c]);
        f0 = v.x; f1 = v.y; f2 = v.z; f3 = v.w;
    } else if (lane < 56) {
        int t = c - S_SCAL;
        int ti = t >> 5, dim = t & 31;
        const int* idx; const float* emb;
        switch (ti) {
            case 0: idx = xo;   emb = eo; break;
            case 1: idx = xsrc; emb = es; break;
            case 2: idx = xsink;emb = ek; break;
            case 3: idx = xstr; emb = eg; break;
            default:idx = xpay; emb = ep; break;
        }
        float a0 = 0.f, a1 = 0.f, a2 = 0.f, a3 = 0.f, cnt = 0.f;
        #pragma unroll
        for (int l = 0; l < L_TOK; ++l) {
            int id = idx[node * L_TOK + l];
            if (id != 0) {
                float4 e = *reinterpret_cast<const float4*>(&emb[id * D_EMB + dim]);
                a0 += e.x; a1 += e.y; a2 += e.z; a3 += e.w; cnt += 1.f;
            }
        }
        float r = 1.f / (cnt + 1e-9f);
        f0 = a0 * r; f1 = a1 * r; f2 = a2 * r; f3 = a3 * r;
    }
    float s = f0 + f1 + f2 + f3;
    float q = f0 * f0 + f1 * f1 + f2 * f2 + f3 * f3;
    #pragma unroll
    for (int off = 32; off; off >>= 1) {
        s += __shfl_xor(s, off);
        q += __shfl_xor(q, off);
    }
    float mu = s * (1.f / (float)TOT);
    float var = q * (1.f / (float)TOT) - mu * mu;
    float rs = rsqrtf(var + 1e-5f);
    if (lane < 56) {
        float4 sc = *reinterpret_cast<const float4*>(&lns[c]);
        float4 bi = *reinterpret_cast<const float4*>(&lnb[c]);
        ushort4 o;
        o.x = f2b((f0 - mu) * rs * sc.x + bi.x);
        o.y = f2b((f1 - mu) * rs * sc.y + bi.y);
        o.z = f2b((f2 - mu) * rs * sc.z + bi.z);
        o.w = f2b((f3 - mu) * rs * sc.w + bi.w);
        *reinterpret_cast<ushort4*>(&x0[(size_t)node * TOT + c]) = o;
    }
}

// ---------------- bf16 MFMA GEMM ----------------
__global__ void gemm_bf16(const unsigned short* __restrict__ A,
                          const unsigned short* __restrict__ BT,
                          unsigned short* __restrict__ C, int M, int N, int K) {
    __shared__ unsigned short As[64][40];
    __shared__ unsigned short Bs[64][40];
    int tid = threadIdx.x;
    int wave = tid >> 6, lane = tid & 63;
    int l15 = lane & 15, kb = lane >> 4;
    int bm = blockIdx.x * 64, bn = blockIdx.y * 64;
    f32x4 acc[4] = {};
    int row_ld = tid >> 2, seg = tid & 3;
    for (int k0 = 0; k0 < K; k0 += 32) {
        {
            const uint4 v = *reinterpret_cast<const uint4*>(&A[(size_t)(bm + row_ld) * K + k0 + seg * 8]);
            *reinterpret_cast<uint4*>(&As[row_ld][seg * 8]) = v;
        }
        {
            const uint4 v = *reinterpret_cast<const uint4*>(&BT[(size_t)(bn + row_ld) * K + k0 + seg * 8]);
            *reinterpret_cast<uint4*>(&Bs[row_ld][seg * 8]) = v;
        }
        __syncthreads();
        bf16x8 af = *reinterpret_cast<const bf16x8*>(&As[wave * 16 + l15][kb * 8]);
        #pragma unroll
        for (int t = 0; t < 4; ++t) {
            bf16x8 bfr = *reinterpret_cast<const bf16x8*>(&Bs[t * 16 + l15][kb * 8]);
            acc[t] = __builtin_amdgcn_mfma_f32_16x16x32_bf16(af, bfr, acc[t], 0, 0, 0);
        }
        __syncthreads();
    }
    #pragma unroll
    for (int t = 0; t < 4; ++t) {
        #pragma unroll
        for (int r = 0; r < 4; ++r) {
            int row = bm + wave * 16 + kb * 4 + r;
            if (row < M)
                C[(size_t)row * N + bn + t * 16 + l15] = f2b(acc[t][r]);
        }
    }
}

// ---------------- attention prep (wave per node, 4 nodes/block) ----------------
__global__ void att_prep1(const unsigned short* __restrict__ h1, const float* __restrict__ asrc,
                          const float* __restrict__ adst, float* __restrict__ s1,
                          float* __restrict__ d1) {
    int node = blockIdx.x * 4 + (threadIdx.x >> 6);
    if (node >= N_NODES) return;
    int lane = threadIdx.x & 63;
    const uint4* h1u4 = (const uint4*)h1;          // row = 64 uint4
    uint4 v = h1u4[(size_t)node * 64 + lane];
    int c = lane * 8, head = lane >> 4;
    float h[8] = { blo(v.x), bhi(v.x), blo(v.y), bhi(v.y),
                   blo(v.z), bhi(v.z), blo(v.w), bhi(v.w) };
    float4 a0 = *reinterpret_cast<const float4*>(&asrc[c]);
    float4 a1 = *reinterpret_cast<const float4*>(&asrc[c + 4]);
    float4 d0 = *reinterpret_cast<const float4*>(&adst[c]);
    float4 d4 = *reinterpret_cast<const float4*>(&adst[c + 4]);
    float sv = h[0]*a0.x + h[1]*a0.y + h[2]*a0.z + h[3]*a0.w
             + h[4]*a1.x + h[5]*a1.y + h[6]*a1.z + h[7]*a1.w;
    float dv = h[0]*d0.x + h[1]*d0.y + h[2]*d0.z + h[3]*d0.w
             + h[4]*d4.x + h[5]*d4.y + h[6]*d4.z + h[7]*d4.w;
    #pragma unroll
    for (int off = 8; off; off >>= 1) { sv += __shfl_xor(sv, off); dv += __shfl_xor(dv, off); }
    if ((lane & 15) == 0) {
        s1[node * H1 + head] = sv;
        d1[node * H1 + head] = dv;
    }
}

__global__ void att_prep2(const unsigned short* __restrict__ h2, const float* __restrict__ asrc,
                          const float* __restrict__ adst, float* __restrict__ s2,
                          float* __restrict__ d2) {
    int node = blockIdx.x * 4 + (threadIdx.x >> 6);
    if (node >= N_NODES) return;
    int lane = threadIdx.x & 63;
    const unsigned* h2u = (const unsigned*)h2;     // row = 64 uints
    unsigned v = h2u[(size_t)node * 64 + lane];
    float h0 = blo(v), h1v = bhi(v);
    float sv = h0 * asrc[2 * lane] + h1v * asrc[2 * lane + 1];
    float dv = h0 * adst[2 * lane] + h1v * adst[2 * lane + 1];
    #pragma unroll
    for (int off = 32; off; off >>= 1) { sv += __shfl_xor(sv, off); dv += __shfl_xor(dv, off); }
    if (lane == 0) { s2[node] = sv; d2[node] = dv; }
}

// ---------------- GAT layer 1: softmax + aggregate + bias + elu ----------------
// 256 thr. Softmax: wave w = head w. Gather: lane l = channels 8l..8l+7 (uint4),
// wave w takes edges w, w+4, ... with 2-stage prefetch. Cross-wave reduce in LDS.
__global__ void gat1_aggregate(const unsigned short* __restrict__ h1, const float* __restrict__ s1,
                               const float* __restrict__ d1, const int* __restrict__ rowptr,
                               const int* __restrict__ csr, const float* __restrict__ b1,
                               unsigned short* __restrict__ x1) {
    int n = blockIdx.x, tid = threadIdx.x;
    int wave = tid >> 6, lane = tid & 63;
    int head = lane >> 4;                     // head owning this lane's 8 channels
    int r0 = rowptr[n], deg = rowptr[n + 1] - r0;
    __shared__ float alpha_sh[H1][68];        // padded: distinct banks across heads
    __shared__ int src_sh[64];
    __shared__ float d_n[H1];
    __shared__ float red[3][512];
    if (tid < H1) d_n[tid] = d1[n * H1 + tid];
    __syncthreads();
    float dnw = d_n[wave];
    const uint4* h1u4 = (const uint4*)h1;     // row = 64 uint4
    float acc[8] = {};

    auto gather = [&](int cnt) {
        int i = wave;
        int srcn; float an; uint4 vn;
        bool have = (i < cnt);
        if (have) {
            srcn = __builtin_amdgcn_readfirstlane(src_sh[i]);
            an = alpha_sh[head][i];
            vn = h1u4[(size_t)srcn * 64 + lane];
        }
        while (have) {
            uint4 v = vn; float a = an;
            int ix = i + 4;
            have = (ix < cnt);
            if (have) {
                srcn = __builtin_amdgcn_readfirstlane(src_sh[ix]);
                an = alpha_sh[head][ix];
                vn = h1u4[(size_t)srcn * 64 + lane];
            }
            acc[0] += a * blo(v.x); acc[1] += a * bhi(v.x);
            acc[2] += a * blo(v.y); acc[3] += a * bhi(v.y);
            acc[4] += a * blo(v.z); acc[5] += a * bhi(v.z);
            acc[6] += a * blo(v.w); acc[7] += a * bhi(v.w);
            i = ix;
        }
    };

    if (deg <= 64) {
        // single-pass softmax in registers (wave = head)
        float e = -1e30f;
        if (lane < deg) {
            int src = csr[r0 + lane];
            if (wave == 0) src_sh[lane] = src;
            float ev = s1[src * H1 + wave] + dnw;
            e = (ev >= 0.f) ? ev : 0.2f * ev;
        }
        float m = e;
        #pragma unroll
        for (int off = 32; off; off >>= 1) m = fmaxf(m, __shfl_xor(m, off));
        float ex = (lane < deg) ? __expf(e - m) : 0.f;
        float den = ex;
        #pragma unroll
        for (int off = 32; off; off >>= 1) den += __shfl_xor(den, off);
        alpha_sh[wave][lane] = ex / den;
        __syncthreads();
        gather(deg);
    } else {
        // generic: strided max + denom (wave = head), then chunked gather
        float m = -1e30f;
        for (int i = lane; i < deg; i += 64) {
            int src = csr[r0 + i];
            float e = s1[src * H1 + wave] + dnw;
            e = (e >= 0.f) ? e : 0.2f * e;
            m = fmaxf(m, e);
        }
        #pragma unroll
        for (int off = 32; off; off >>= 1) m = fmaxf(m, __shfl_xor(m, off));
        float den = 0.f;
        for (int i = lane; i < deg; i += 64) {
            int src = csr[r0 + i];
            float e = s1[src * H1 + wave] + dnw;
            e = (e >= 0.f) ? e : 0.2f * e;
            den += __expf(e - m);
        }
        #pragma unroll
        for (int off = 32; off; off >>= 1) den += __shfl_xor(den, off);
        float invw = 1.f / den;
        for (int c0 = 0; c0 < deg; c0 += 64) {
            __syncthreads();
            int i = c0 + lane;
            if (i < deg) {
                int src = csr[r0 + i];
                if (wave == 0) src_sh[lane] = src;
                float e = s1[src * H1 + wave] + dnw;
                e = (e >= 0.f) ? e : 0.2f * e;
                alpha_sh[wave][lane] = __expf(e - m) * invw;
            }
            __syncthreads();
            gather(min(64, deg - c0));
        }
    }
    // cross-wave reduce + epilogue
    if (wave > 0) {
        *reinterpret_cast<float4*>(&red[wave - 1][lane * 8]) =
            make_float4(acc[0], acc[1], acc[2], acc[3]);
        *reinterpret_cast<float4*>(&red[wave - 1][lane * 8 + 4]) =
            make_float4(acc[4], acc[5], acc[6], acc[7]);
    }
    __syncthreads();
    if (wave == 0) {
        #pragma unroll
        for (int w = 0; w < 3; ++w) {
            float4 p = *reinterpret_cast<float4*>(&red[w][lane * 8]);
            float4 q = *reinterpret_cast<float4*>(&red[w][lane * 8 + 4]);
            acc[0] += p.x; acc[1] += p.y; acc[2] += p.z; acc[3] += p.w;
            acc[4] += q.x; acc[5] += q.y; acc[6] += q.z; acc[7] += q.w;
        }
        float4 b0 = *reinterpret_cast<const float4*>(&b1[lane * 8]);
        float4 b4 = *reinterpret_cast<const float4*>(&b1[lane * 8 + 4]);
        float v0 = acc[0] + b0.x; v0 = (v0 > 0.f) ? v0 : expm1f(v0);
        float v1 = acc[1] + b0.y; v1 = (v1 > 0.f) ? v1 : expm1f(v1);
        float v2 = acc[2] + b0.z; v2 = (v2 > 0.f) ? v2 : expm1f(v2);
        float v3 = acc[3] + b0.w; v3 = (v3 > 0.f) ? v3 : expm1f(v3);
        float v4 = acc[4] + b4.x; v4 = (v4 > 0.f) ? v4 : expm1f(v4);
        float v5 = acc[5] + b4.y; v5 = (v5 > 0.f) ? v5 : expm1f(v5);
        float v6 = acc[6] + b4.z; v6 = (v6 > 0.f) ? v6 : expm1f(v6);
        float v7 = acc[7] + b4.w; v7 = (v7 > 0.f) ? v7 : expm1f(v7);
        uint4 pk;
        pk.x = (unsigned)f2b(v0) | ((unsigned)f2b(v1) << 16);
        pk.y = (unsigned)f2b(v2) | ((unsigned)f2b(v3) << 16);
        pk.z = (unsigned)f2b(v4) | ((unsigned)f2b(v5) << 16);
        pk.w = (unsigned)f2b(v6) | ((unsigned)f2b(v7) << 16);
        ((uint4*)x1)[(size_t)n * 64 + lane] = pk;
    }
}

// ---------------- GAT layer 2 per-node output (no atomics) ----------------
// 128 thr. 16-lane group g owns full 128-ch row (uint4/lane), edges g, g+8, ...
__global__ void gat2_node(const unsigned short* __restrict__ h2, const float* __restrict__ s2,
                          const float* __restrict__ d2, const int* __restrict__ rowptr,
                          const int* __restrict__ csr, const float* __restrict__ b2,
                          float* __restrict__ h2act) {
    int n = blockIdx.x, tid = threadIdx.x;   // 128 threads
    int wid = tid >> 6, lane = tid & 63;
    int grp = tid >> 4, l16 = tid & 15;
    int r0 = rowptr[n], deg = rowptr[n + 1] - r0;
    __shared__ float alpha_sh[128];
    __shared__ int src_sh[128];
    __shared__ float rA[2], rB[2];
    __shared__ float red[8][128];
    float dn = d2[n];
    const uint4* h2u4 = (const uint4*)h2;    // row = 16 uint4
    float acc[8] = {};

    auto gather = [&](int cnt) {
        int i = grp;
        int srcn; float an; uint4 vn;
        bool have = (i < cnt);
        if (have) {
            srcn = src_sh[i];                // broadcast per 16-lane group
            an = alpha_sh[i];
            vn = h2u4[(size_t)srcn * 16 + l16];
        }
        while (have) {
            uint4 v = vn; float a = an;
            int ix = i + 8;
            have = (ix < cnt);
            if (have) {
                srcn = src_sh[ix];
                an = alpha_sh[ix];
                vn = h2u4[(size_t)srcn * 16 + l16];
            }
            acc[0] += a * blo(v.x); acc[1] += a * bhi(v.x);
            acc[2] += a * blo(v.y); acc[3] += a * bhi(v.y);
            acc[4] += a * blo(v.z); acc[5] += a * bhi(v.z);
            acc[6] += a * blo(v.w); acc[7] += a * bhi(v.w);
            i = ix;
        }
    };

    if (deg <= 128) {
        float e = -1e30f;
        if (tid < deg) {
            int src = csr[r0 + tid];
            src_sh[tid] = src;
            float ev = s2[src] + dn;
            e = (ev >= 0.f) ? ev : 0.2f * ev;
        }
        float m = e;
        #pragma unroll
        for (int off = 32; off; off >>= 1) m = fmaxf(m, __shfl_xor(m, off));
        if (lane == 0) rA[wid] = m;
        __syncthreads();
        m = fmaxf(rA[0], rA[1]);
        float ex = (tid < deg) ? __expf(e - m) : 0.f;
        float den = ex;
        #pragma unroll
        for (int off = 32; off; off >>= 1) den += __shfl_xor(den, off);
        if (lane == 0) rB[wid] = den;
        __syncthreads();
        den = rB[0] + rB[1];
        alpha_sh[tid] = ex / den;
        __syncthreads();
        gather(deg);
    } else {
        float m = -1e30f;
        for (int i = tid; i < deg; i += 128) {
            float e = s2[csr[r0 + i]] + dn; e = (e >= 0.f) ? e : 0.2f * e;
            m = fmaxf(m, e);
        }
        #pragma unroll
        for (int off = 32; off; off >>= 1) m = fmaxf(m, __shfl_xor(m, off));
        if (lane == 0) rA[wid] = m;
        __syncthreads();
        m = fmaxf(rA[0], rA[1]);
        float den = 0.f;
        for (int i = tid; i < deg; i += 128) {
            float e = s2[csr[r0 + i]] + dn; e = (e >= 0.f) ? e : 0.2f * e;
            den += __expf(e - m);
        }
        #pragma unroll
        for (int off = 32; off; off >>= 1) den += __shfl_xor(den, off);
        if (lane == 0) rB[wid] = den;
        __syncthreads();
        den = rB[0] + rB[1];
        float inv = 1.f / den;
        for (int c0 = 0; c0 < deg; c0 += 128) {
            __syncthreads();
            int i = c0 + tid;
            if (i < deg) {
                int src = csr[r0 + i];
                src_sh[tid] = src;
                float e = s2[src] + dn; e = (e >= 0.f) ? e : 0.2f * e;
                alpha_sh[tid] = __expf(e - m) * inv;
            }
            __syncthreads();
            gather(min(128, deg - c0));
        }
    }
    // cross-group reduce + epilogue
    *reinterpret_cast<float4*>(&red[grp][l16 * 8]) =
        make_float4(acc[0], acc[1], acc[2], acc[3]);
    *reinterpret_cast<float4*>(&red[grp][l16 * 8 + 4]) =
        make_float4(acc[4], acc[5], acc[6], acc[7]);
    __syncthreads();
    float s = red[0][tid] + red[1][tid] + red[2][tid] + red[3][tid]
            + red[4][tid] + red[5][tid] + red[6][tid] + red[7][tid] + b2[tid];
    s = (s > 0.f) ? s : expm1f(s);
    h2act[(size_t)n * F2 + tid] = s;
}

// ---------------- per-graph max-pool (batch sorted -> contiguous ranges) ----------------
__global__ void graph_pool(const float* __restrict__ h2act, const int* __restrict__ batch,
                           float* __restrict__ out) {
    int gph = blockIdx.x;                     // 64 blocks
    int tid = threadIdx.x;                    // 256: noff = tid>>7, ch = tid&127
    __shared__ int se[2];
    __shared__ float red[128];
    if (tid < 2) {
        int target = gph + tid;               // first index with batch[i] >= target
        int lo = 0, hi = N_NODES;
        while (lo < hi) { int mid = (lo + hi) >> 1; if (batch[mid] < target) lo = mid + 1; else hi = mid; }
        se[tid] = lo;
    }
    __syncthreads();
    int start = se[0], end = se[1];
    int ch = tid & 127, noff = tid >> 7;
    float m = -INFINITY;
    for (int i = start + noff; i < end; i += 2)
        m = fmaxf(m, h2act[(size_t)i * F2 + ch]);
    if (noff == 1) red[ch] = m;
    __syncthreads();
    if (noff == 0) out[gph * F2 + ch] = fmaxf(m, red[ch]);
}

// ---------------- launcher ----------------
extern "C" void kernel_launch(void* const* d_in, const int* in_sizes, int n_in,
                              void* d_out, int out_size, void* d_ws, size_t ws_size,
                              hipStream_t stream) {
    const float* x_scalar = (const float*)d_in[0];
    const int*   x_opcode = (const int*)d_in[1];
    const int*   x_source = (const int*)d_in[2];
    const int*   x_sink   = (const int*)d_in[3];
    const int*   x_string = (const int*)d_in[4];
    const int*   x_payload= (const int*)d_in[5];
    const int*   edge_idx = (const int*)d_in[6];
    const int*   batch    = (const int*)d_in[7];
    const float* emb_op   = (const float*)d_in[8];
    const float* emb_src  = (const float*)d_in[9];
    const float* emb_snk  = (const float*)d_in[10];
    const float* emb_str  = (const float*)d_in[11];
    const float* emb_pay  = (const float*)d_in[12];
    const float* ln_scale = (const float*)d_in[13];
    const float* ln_bias  = (const float*)d_in[14];
    const float* W1       = (const float*)d_in[15];
    const float* att_src1 = (const float*)d_in[16];
    const float* att_dst1 = (const float*)d_in[17];
    const float* b1       = (const float*)d_in[18];
    const float* W2       = (const float*)d_in[19];
    const float* att_src2 = (const float*)d_in[20];
    const float* att_dst2 = (const float*)d_in[21];
    const float* b2       = (const float*)d_in[22];
    float* out = (float*)d_out;

    // workspace layout
    unsigned short* x0  = (unsigned short*)d_ws;               // M_PAD*224 bf16
    unsigned short* h1  = x0 + (size_t)M_PAD * TOT;            // M_PAD*512
    unsigned short* x1  = h1 + (size_t)M_PAD * F1;             // M_PAD*512
    unsigned short* h2  = x1 + (size_t)M_PAD * F1;             // M_PAD*128
    unsigned short* W1T = h2 + (size_t)M_PAD * F2;             // 512*224
    unsigned short* W2T = W1T + (size_t)F1 * TOT;              // 128*512
    float* s1 = (float*)(W2T + (size_t)F2 * F1);               // N*4
    float* d1 = s1 + (size_t)N_NODES * H1;
    float* s2 = d1 + (size_t)N_NODES * H1;                     // N
    float* d2 = s2 + N_NODES;
    int* rowptr = (int*)(d2 + N_NODES);                        // N+1
    int* cursor = rowptr + (N_NODES + 1);                      // N+1
    int* csr    = cursor + (N_NODES + 1);                      // E_TOT
    float* h2act = (float*)x1;                                 // alias: x1 dead after gemm2

    // CSR build
    init_deg<<<(N_NODES + 255) / 256, 256, 0, stream>>>(cursor);
    add_deg<<<(N_EDGES + 255) / 256, 256, 0, stream>>>(edge_idx, cursor);
    scan_deg<<<1, 1024, 0, stream>>>(cursor, rowptr, cursor);
    scatter_edges<<<(E_TOT + 255) / 256, 256, 0, stream>>>(edge_idx, cursor, csr);

    // weight transposes
    transpose_cast<<<(TOT * F1 + 255) / 256, 256, 0, stream>>>(W1, W1T, TOT, F1);
    transpose_cast<<<(F1 * F2 + 255) / 256, 256, 0, stream>>>(W2, W2T, F1, F2);

    // features + LN
    feat_ln<<<(N_NODES + 3) / 4, 256, 0, stream>>>(x_scalar, x_opcode, x_source, x_sink,
                                                   x_string, x_payload, emb_op, emb_src,
                                                   emb_snk, emb_str, emb_pay, ln_scale,
                                                   ln_bias, x0);

    // layer 1
    dim3 g1(M_PAD / 64, F1 / 64);
    gemm_bf16<<<g1, 256, 0, stream>>>(x0, W1T, h1, N_NODES, F1, TOT);
    att_prep1<<<(N_NODES + 3) / 4, 256, 0, stream>>>(h1, att_src1, att_dst1, s1, d1);
    gat1_aggregate<<<N_NODES, 256, 0, stream>>>(h1, s1, d1, rowptr, csr, b1, x1);

    // layer 2
    dim3 g2(M_PAD / 64, F2 / 64);
    gemm_bf16<<<g2, 256, 0, stream>>>(x1, W2T, h2, N_NODES, F2, F1);
    att_prep2<<<(N_NODES + 3) / 4, 256, 0, stream>>>(h2, att_src2, att_dst2, s2, d2);

    gat2_node<<<N_NODES, 128, 0, stream>>>(h2, s2, d2, rowptr, csr, b2, h2act);
    graph_pool<<<N_GRAPH, 256, 0, stream>>>(h2act, batch, out);
}

// Round 8
// 342.881 us; speedup vs baseline: 1.3872x; 1.0019x over previous
//
#include <hip/hip_runtime.h>
#include <hip/hip_bf16.h>
#include <math.h>

#define N_NODES 30000
#define M_PAD   30016     // 469*64
#define N_EDGES 480000
#define N_GRAPH 64
#define L_TOK   20
#define D_EMB   32
#define S_SCAL  64
#define TOT     224      // S + 5*D, = 7*32
#define H1      4
#define C1      128
#define F1      512      // H1*C1
#define F2      128
#define E_TOT   (N_EDGES + N_NODES)

typedef __attribute__((ext_vector_type(8))) short bf16x8;
typedef __attribute__((ext_vector_type(4))) float f32x4;

__device__ __forceinline__ unsigned short f2b(float f) {
    unsigned u = __float_as_uint(f);
    u += 0x7FFFu + ((u >> 16) & 1u);
    return (unsigned short)(u >> 16);
}
__device__ __forceinline__ float b2f(unsigned short h) {
    return __uint_as_float(((unsigned)h) << 16);
}
__device__ __forceinline__ float blo(unsigned u) { return __uint_as_float(u << 16); }
__device__ __forceinline__ float bhi(unsigned u) { return __uint_as_float(u & 0xFFFF0000u); }

// ---------------- CSR build ----------------
__global__ void init_deg(int* deg) {
    int i = blockIdx.x * blockDim.x + threadIdx.x;
    if (i < N_NODES) deg[i] = 1;   // self loop
}

__global__ void add_deg(const int* __restrict__ ei, int* deg) {
    int e = blockIdx.x * blockDim.x + threadIdx.x;
    if (e < N_EDGES) atomicAdd(&deg[ei[N_EDGES + e]], 1);
}

#define SCAN_PER 30
__global__ void scan_deg(const int* __restrict__ deg, int* __restrict__ rowptr,
                         int* __restrict__ cursor) {
    int t = threadIdx.x, lane = t & 63, wid = t >> 6;   // 16 waves
    int base = t * SCAN_PER;
    int v[SCAN_PER];
    int lsum = 0;
    #pragma unroll
    for (int i = 0; i < SCAN_PER; ++i) {
        int ii = base + i;
        int d = (ii < N_NODES) ? deg[ii] : 0;
        v[i] = lsum;
        lsum += d;
    }
    int incl = lsum;
    #pragma unroll
    for (int off = 1; off < 64; off <<= 1) {
        int u = __shfl_up(incl, off);
        if (lane >= off) incl += u;
    }
    __shared__ int wsum[16], woff[16];
    if (lane == 63) wsum[wid] = incl;
    __syncthreads();
    if (t == 0) {
        int run = 0;
        #pragma unroll
        for (int w = 0; w < 16; ++w) { woff[w] = run; run += wsum[w]; }
        rowptr[N_NODES] = run;
    }
    __syncthreads();
    int texcl = woff[wid] + (incl - lsum);
    #pragma unroll
    for (int i = 0; i < SCAN_PER; ++i) {
        int ii = base + i;
        if (ii < N_NODES) { int p = texcl + v[i]; rowptr[ii] = p; cursor[ii] = p; }
    }
}

__global__ void scatter_edges(const int* __restrict__ ei, int* cursor, int* csr_src) {
    int e = blockIdx.x * blockDim.x + threadIdx.x;
    if (e < N_EDGES) {
        int src = ei[e], dst = ei[N_EDGES + e];
        int pos = atomicAdd(&cursor[dst], 1);
        csr_src[pos] = src;
    } else if (e < E_TOT) {
        int n = e - N_EDGES;
        int pos = atomicAdd(&cursor[n], 1);
        csr_src[pos] = n;
    }
}

// ---------------- weight transpose+cast ----------------
__global__ void transpose_cast(const float* __restrict__ W, unsigned short* __restrict__ WT,
                               int K, int N) {
    int idx = blockIdx.x * blockDim.x + threadIdx.x;
    if (idx < K * N) {
        int n = idx / K, k = idx - n * K;
        WT[idx] = f2b(W[(size_t)k * N + n]);
    }
}

// ---------------- features + layernorm (bf16 out), wave-per-node ----------------
__global__ void feat_ln(const float* __restrict__ xs,
                        const int* __restrict__ xo, const int* __restrict__ xsrc,
                        const int* __restrict__ xsink, const int* __restrict__ xstr,
                        const int* __restrict__ xpay,
                        const float* __restrict__ eo, const float* __restrict__ es,
                        const float* __restrict__ ek, const float* __restrict__ eg,
                        const float* __restrict__ ep,
                        const float* __restrict__ lns, const float* __restrict__ lnb,
                        unsigned short* __restrict__ x0) {
    int node = blockIdx.x * 4 + (threadIdx.x >> 6);
    if (node >= N_NODES) return;
    int lane = threadIdx.x & 63;
    int c = lane * 4;
    float f0 = 0.f, f1 = 0.f, f2 = 0.f, f3 = 0.f;
    if (lane < 16) {
        float4 v = *reinterpret_cast<const float4*>(&xs[(size_t)node * S_SCAL + c]);
        f0 = v.x; f1 = v.y; f2 = v.z; f3 = v.w;
    } else if (lane < 56) {
        int t = c - S_SCAL;
        int ti = t >> 5, dim = t & 31;
        const int* idx; const float* emb;
        switch (ti) {
            case 0: idx = xo;   emb = eo; break;
            case 1: idx = xsrc; emb = es; break;
            case 2: idx = xsink;emb = ek; break;
            case 3: idx = xstr; emb = eg; break;
            default:idx = xpay; emb = ep; break;
        }
        float a0 = 0.f, a1 = 0.f, a2 = 0.f, a3 = 0.f, cnt = 0.f;
        #pragma unroll
        for (int l = 0; l < L_TOK; ++l) {
            int id = idx[node * L_TOK + l];
            if (id != 0) {
                float4 e = *reinterpret_cast<const float4*>(&emb[id * D_EMB + dim]);
                a0 += e.x; a1 += e.y; a2 += e.z; a3 += e.w; cnt += 1.f;
            }
        }
        float r = 1.f / (cnt + 1e-9f);
        f0 = a0 * r; f1 = a1 * r; f2 = a2 * r; f3 = a3 * r;
    }
    float s = f0 + f1 + f2 + f3;
    float q = f0 * f0 + f1 * f1 + f2 * f2 + f3 * f3;
    #pragma unroll
    for (int off = 32; off; off >>= 1) {
        s += __shfl_xor(s, off);
        q += __shfl_xor(q, off);
    }
    float mu = s * (1.f / (float)TOT);
    float var = q * (1.f / (float)TOT) - mu * mu;
    float rs = rsqrtf(var + 1e-5f);
    if (lane < 56) {
        float4 sc = *reinterpret_cast<const float4*>(&lns[c]);
        float4 bi = *reinterpret_cast<const float4*>(&lnb[c]);
        ushort4 o;
        o.x = f2b((f0 - mu) * rs * sc.x + bi.x);
        o.y = f2b((f1 - mu) * rs * sc.y + bi.y);
        o.z = f2b((f2 - mu) * rs * sc.z + bi.z);
        o.w = f2b((f3 - mu) * rs * sc.w + bi.w);
        *reinterpret_cast<ushort4*>(&x0[(size_t)node * TOT + c]) = o;
    }
}

// ---------------- bf16 MFMA GEMM ----------------
__global__ void gemm_bf16(const unsigned short* __restrict__ A,
                          const unsigned short* __restrict__ BT,
                          unsigned short* __restrict__ C, int M, int N, int K) {
    __shared__ unsigned short As[64][40];
    __shared__ unsigned short Bs[64][40];
    int tid = threadIdx.x;
    int wave = tid >> 6, lane = tid & 63;
    int l15 = lane & 15, kb = lane >> 4;
    int bm = blockIdx.x * 64, bn = blockIdx.y * 64;
    f32x4 acc[4] = {};
    int row_ld = tid >> 2, seg = tid & 3;
    for (int k0 = 0; k0 < K; k0 += 32) {
        {
            const uint4 v = *reinterpret_cast<const uint4*>(&A[(size_t)(bm + row_ld) * K + k0 + seg * 8]);
            *reinterpret_cast<uint4*>(&As[row_ld][seg * 8]) = v;
        }
        {
            const uint4 v = *reinterpret_cast<const uint4*>(&BT[(size_t)(bn + row_ld) * K + k0 + seg * 8]);
            *reinterpret_cast<uint4*>(&Bs[row_ld][seg * 8]) = v;
        }
        __syncthreads();
        bf16x8 af = *reinterpret_cast<const bf16x8*>(&As[wave * 16 + l15][kb * 8]);
        #pragma unroll
        for (int t = 0; t < 4; ++t) {
            bf16x8 bfr = *reinterpret_cast<const bf16x8*>(&Bs[t * 16 + l15][kb * 8]);
            acc[t] = __builtin_amdgcn_mfma_f32_16x16x32_bf16(af, bfr, acc[t], 0, 0, 0);
        }
        __syncthreads();
    }
    #pragma unroll
    for (int t = 0; t < 4; ++t) {
        #pragma unroll
        for (int r = 0; r < 4; ++r) {
            int row = bm + wave * 16 + kb * 4 + r;
            if (row < M)
                C[(size_t)row * N + bn + t * 16 + l15] = f2b(acc[t][r]);
        }
    }
}

// ---------------- attention prep (wave per node, 4 nodes/block) ----------------
__global__ void att_prep1(const unsigned short* __restrict__ h1, const float* __restrict__ asrc,
                          const float* __restrict__ adst, float* __restrict__ s1,
                          float* __restrict__ d1) {
    int node = blockIdx.x * 4 + (threadIdx.x >> 6);
    if (node >= N_NODES) return;
    int lane = threadIdx.x & 63;
    const uint4* h1u4 = (const uint4*)h1;          // row = 64 uint4
    uint4 v = h1u4[(size_t)node * 64 + lane];
    int c = lane * 8, head = lane >> 4;
    float h[8] = { blo(v.x), bhi(v.x), blo(v.y), bhi(v.y),
                   blo(v.z), bhi(v.z), blo(v.w), bhi(v.w) };
    float4 a0 = *reinterpret_cast<const float4*>(&asrc[c]);
    float4 a1 = *reinterpret_cast<const float4*>(&asrc[c + 4]);
    float4 d0 = *reinterpret_cast<const float4*>(&adst[c]);
    float4 d4 = *reinterpret_cast<const float4*>(&adst[c + 4]);
    float sv = h[0]*a0.x + h[1]*a0.y + h[2]*a0.z + h[3]*a0.w
             + h[4]*a1.x + h[5]*a1.y + h[6]*a1.z + h[7]*a1.w;
    float dv = h[0]*d0.x + h[1]*d0.y + h[2]*d0.z + h[3]*d0.w
             + h[4]*d4.x + h[5]*d4.y + h[6]*d4.z + h[7]*d4.w;
    #pragma unroll
    for (int off = 8; off; off >>= 1) { sv += __shfl_xor(sv, off); dv += __shfl_xor(dv, off); }
    if ((lane & 15) == 0) {
        s1[node * H1 + head] = sv;
        d1[node * H1 + head] = dv;
    }
}

__global__ void att_prep2(const unsigned short* __restrict__ h2, const float* __restrict__ asrc,
                          const float* __restrict__ adst, float* __restrict__ s2,
                          float* __restrict__ d2) {
    int node = blockIdx.x * 4 + (threadIdx.x >> 6);
    if (node >= N_NODES) return;
    int lane = threadIdx.x & 63;
    const unsigned* h2u = (const unsigned*)h2;     // row = 64 uints
    unsigned v = h2u[(size_t)node * 64 + lane];
    float h0 = blo(v), h1v = bhi(v);
    float sv = h0 * asrc[2 * lane] + h1v * asrc[2 * lane + 1];
    float dv = h0 * adst[2 * lane] + h1v * adst[2 * lane + 1];
    #pragma unroll
    for (int off = 32; off; off >>= 1) { sv += __shfl_xor(sv, off); dv += __shfl_xor(dv, off); }
    if (lane == 0) { s2[node] = sv; d2[node] = dv; }
}

// ---------------- GAT layer 1: softmax + aggregate + bias + elu ----------------
// 256 thr. Softmax: wave w = head w. Gather: lane l = channels 8l..8l+7 (uint4),
// wave w owns edges w+4j; 4 prefetch streams (stride 16). Cross-wave reduce in LDS.
#define ACC8(v, a) \
    acc[0] += (a) * blo((v).x); acc[1] += (a) * bhi((v).x); \
    acc[2] += (a) * blo((v).y); acc[3] += (a) * bhi((v).y); \
    acc[4] += (a) * blo((v).z); acc[5] += (a) * bhi((v).z); \
    acc[6] += (a) * blo((v).w); acc[7] += (a) * bhi((v).w);

__global__ void gat1_aggregate(const unsigned short* __restrict__ h1, const float* __restrict__ s1,
                               const float* __restrict__ d1, const int* __restrict__ rowptr,
                               const int* __restrict__ csr, const float* __restrict__ b1,
                               unsigned short* __restrict__ x1) {
    int n = blockIdx.x, tid = threadIdx.x;
    int wave = tid >> 6, lane = tid & 63;
    int head = lane >> 4;                     // head owning this lane's 8 channels
    int r0 = rowptr[n], deg = rowptr[n + 1] - r0;
    __shared__ float alpha_sh[H1][68];        // padded: distinct banks across heads
    __shared__ int src_sh[64];
    __shared__ float d_n[H1];
    __shared__ float red[3][512];
    if (tid < H1) d_n[tid] = d1[n * H1 + tid];
    __syncthreads();
    float dnw = d_n[wave];
    const uint4* h1u4 = (const uint4*)h1;     // row = 64 uint4
    float acc[8] = {};

    auto gather = [&](int cnt) {
        int iA = wave, iB = wave + 4, iC = wave + 8, iD = wave + 12;
        bool hA = iA < cnt, hB = iB < cnt, hC = iC < cnt, hD = iD < cnt;
        int s; float aA, aB, aC, aD; uint4 vA, vB, vC, vD;
        if (hA) { s = __builtin_amdgcn_readfirstlane(src_sh[iA]); aA = alpha_sh[head][iA]; vA = h1u4[(size_t)s * 64 + lane]; }
        if (hB) { s = __builtin_amdgcn_readfirstlane(src_sh[iB]); aB = alpha_sh[head][iB]; vB = h1u4[(size_t)s * 64 + lane]; }
        if (hC) { s = __builtin_amdgcn_readfirstlane(src_sh[iC]); aC = alpha_sh[head][iC]; vC = h1u4[(size_t)s * 64 + lane]; }
        if (hD) { s = __builtin_amdgcn_readfirstlane(src_sh[iD]); aD = alpha_sh[head][iD]; vD = h1u4[(size_t)s * 64 + lane]; }
        while (hA) {
            {
                uint4 v = vA; float a = aA;
                iA += 16; hA = iA < cnt;
                if (hA) { s = __builtin_amdgcn_readfirstlane(src_sh[iA]); aA = alpha_sh[head][iA]; vA = h1u4[(size_t)s * 64 + lane]; }
                ACC8(v, a)
            }
            if (hB) {
                uint4 v = vB; float a = aB;
                iB += 16; hB = iB < cnt;
                if (hB) { s = __builtin_amdgcn_readfirstlane(src_sh[iB]); aB = alpha_sh[head][iB]; vB = h1u4[(size_t)s * 64 + lane]; }
                ACC8(v, a)
            }
            if (hC) {
                uint4 v = vC; float a = aC;
                iC += 16; hC = iC < cnt;
                if (hC) { s = __builtin_amdgcn_readfirstlane(src_sh[iC]); aC = alpha_sh[head][iC]; vC = h1u4[(size_t)s * 64 + lane]; }
                ACC8(v, a)
            }
            if (hD) {
                uint4 v = vD; float a = aD;
                iD += 16; hD = iD < cnt;
                if (hD) { s = __builtin_amdgcn_readfirstlane(src_sh[iD]); aD = alpha_sh[head][iD]; vD = h1u4[(size_t)s * 64 + lane]; }
                ACC8(v, a)
            }
        }
    };

    if (deg <= 64) {
        // single-pass softmax in registers (wave = head)
        float e = -1e30f;
        if (lane < deg) {
            int src = csr[r0 + lane];
            if (wave == 0) src_sh[lane] = src;
            float ev = s1[src * H1 + wave] + dnw;
            e = (ev >= 0.f) ? ev : 0.2f * ev;
        }
        float m = e;
        #pragma unroll
        for (int off = 32; off; off >>= 1) m = fmaxf(m, __shfl_xor(m, off));
        float ex = (lane < deg) ? __expf(e - m) : 0.f;
        float den = ex;
        #pragma unroll
        for (int off = 32; off; off >>= 1) den += __shfl_xor(den, off);
        alpha_sh[wave][lane] = ex / den;
        __syncthreads();
        gather(deg);
    } else {
        // generic: strided max + denom (wave = head), then chunked gather
        float m = -1e30f;
        for (int i = lane; i < deg; i += 64) {
            int src = csr[r0 + i];
            float e = s1[src * H1 + wave] + dnw;
            e = (e >= 0.f) ? e : 0.2f * e;
            m = fmaxf(m, e);
        }
        #pragma unroll
        for (int off = 32; off; off >>= 1) m = fmaxf(m, __shfl_xor(m, off));
        float den = 0.f;
        for (int i = lane; i < deg; i += 64) {
            int src = csr[r0 + i];
            float e = s1[src * H1 + wave] + dnw;
            e = (e >= 0.f) ? e : 0.2f * e;
            den += __expf(e - m);
        }
        #pragma unroll
        for (int off = 32; off; off >>= 1) den += __shfl_xor(den, off);
        float invw = 1.f / den;
        for (int c0 = 0; c0 < deg; c0 += 64) {
            __syncthreads();
            int i = c0 + lane;
            if (i < deg) {
                int src = csr[r0 + i];
                if (wave == 0) src_sh[lane] = src;
                float e = s1[src * H1 + wave] + dnw;
                e = (e >= 0.f) ? e : 0.2f * e;
                alpha_sh[wave][lane] = __expf(e - m) * invw;
            }
            __syncthreads();
            gather(min(64, deg - c0));
        }
    }
    // cross-wave reduce (conflict-free: 16B/lane contiguous) + epilogue
    if (wave > 0) {
        *reinterpret_cast<float4*>(&red[wave - 1][lane * 4]) =
            make_float4(acc[0], acc[1], acc[2], acc[3]);
        *reinterpret_cast<float4*>(&red[wave - 1][256 + lane * 4]) =
            make_float4(acc[4], acc[5], acc[6], acc[7]);
    }
    __syncthreads();
    if (wave == 0) {
        #pragma unroll
        for (int w = 0; w < 3; ++w) {
            float4 p = *reinterpret_cast<float4*>(&red[w][lane * 4]);
            float4 q = *reinterpret_cast<float4*>(&red[w][256 + lane * 4]);
            acc[0] += p.x; acc[1] += p.y; acc[2] += p.z; acc[3] += p.w;
            acc[4] += q.x; acc[5] += q.y; acc[6] += q.z; acc[7] += q.w;
        }
        float4 b0 = *reinterpret_cast<const float4*>(&b1[lane * 8]);
        float4 b4 = *reinterpret_cast<const float4*>(&b1[lane * 8 + 4]);
        float v0 = acc[0] + b0.x; v0 = (v0 > 0.f) ? v0 : expm1f(v0);
        float v1 = acc[1] + b0.y; v1 = (v1 > 0.f) ? v1 : expm1f(v1);
        float v2 = acc[2] + b0.z; v2 = (v2 > 0.f) ? v2 : expm1f(v2);
        float v3 = acc[3] + b0.w; v3 = (v3 > 0.f) ? v3 : expm1f(v3);
        float v4 = acc[4] + b4.x; v4 = (v4 > 0.f) ? v4 : expm1f(v4);
        float v5 = acc[5] + b4.y; v5 = (v5 > 0.f) ? v5 : expm1f(v5);
        float v6 = acc[6] + b4.z; v6 = (v6 > 0.f) ? v6 : expm1f(v6);
        float v7 = acc[7] + b4.w; v7 = (v7 > 0.f) ? v7 : expm1f(v7);
        uint4 pk;
        pk.x = (unsigned)f2b(v0) | ((unsigned)f2b(v1) << 16);
        pk.y = (unsigned)f2b(v2) | ((unsigned)f2b(v3) << 16);
        pk.z = (unsigned)f2b(v4) | ((unsigned)f2b(v5) << 16);
        pk.w = (unsigned)f2b(v6) | ((unsigned)f2b(v7) << 16);
        ((uint4*)x1)[(size_t)n * 64 + lane] = pk;
    }
}

// ---------------- GAT layer 2 per-node output (no atomics) ----------------
// 128 thr. 16-lane group g owns full 128-ch row (uint4/lane), edges g+8j; 2 streams.
__global__ void gat2_node(const unsigned short* __restrict__ h2, const float* __restrict__ s2,
                          const float* __restrict__ d2, const int* __restrict__ rowptr,
                          const int* __restrict__ csr, const float* __restrict__ b2,
                          float* __restrict__ h2act) {
    int n = blockIdx.x, tid = threadIdx.x;   // 128 threads
    int wid = tid >> 6, lane = tid & 63;
    int grp = tid >> 4, l16 = tid & 15;
    int r0 = rowptr[n], deg = rowptr[n + 1] - r0;
    __shared__ float alpha_sh[128];
    __shared__ int src_sh[128];
    __shared__ float rA[2], rB[2];
    __shared__ float red[8][128];
    float dn = d2[n];
    const uint4* h2u4 = (const uint4*)h2;    // row = 16 uint4
    float acc[8] = {};

    auto gather = [&](int cnt) {
        int iA = grp, iB = grp + 8;
        bool hA = iA < cnt, hB = iB < cnt;
        int sA, sB; float aA, aB; uint4 vA, vB;
        if (hA) { sA = src_sh[iA]; aA = alpha_sh[iA]; vA = h2u4[(size_t)sA * 16 + l16]; }
        if (hB) { sB = src_sh[iB]; aB = alpha_sh[iB]; vB = h2u4[(size_t)sB * 16 + l16]; }
        while (hA) {
            {
                uint4 v = vA; float a = aA;
                iA += 16; hA = iA < cnt;
                if (hA) { sA = src_sh[iA]; aA = alpha_sh[iA]; vA = h2u4[(size_t)sA * 16 + l16]; }
                ACC8(v, a)
            }
            if (hB) {
                uint4 v = vB; float a = aB;
                iB += 16; hB = iB < cnt;
                if (hB) { sB = src_sh[iB]; aB = alpha_sh[iB]; vB = h2u4[(size_t)sB * 16 + l16]; }
                ACC8(v, a)
            }
        }
    };

    if (deg <= 128) {
        float e = -1e30f;
        if (tid < deg) {
            int src = csr[r0 + tid];
            src_sh[tid] = src;
            float ev = s2[src] + dn;
            e = (ev >= 0.f) ? ev : 0.2f * ev;
        }
        float m = e;
        #pragma unroll
        for (int off = 32; off; off >>= 1) m = fmaxf(m, __shfl_xor(m, off));
        if (lane == 0) rA[wid] = m;
        __syncthreads();
        m = fmaxf(rA[0], rA[1]);
        float ex = (tid < deg) ? __expf(e - m) : 0.f;
        float den = ex;
        #pragma unroll
        for (int off = 32; off; off >>= 1) den += __shfl_xor(den, off);
        if (lane == 0) rB[wid] = den;
        __syncthreads();
        den = rB[0] + rB[1];
        alpha_sh[tid] = ex / den;
        __syncthreads();
        gather(deg);
    } else {
        float m = -1e30f;
        for (int i = tid; i < deg; i += 128) {
            float e = s2[csr[r0 + i]] + dn; e = (e >= 0.f) ? e : 0.2f * e;
            m = fmaxf(m, e);
        }
        #pragma unroll
        for (int off = 32; off; off >>= 1) m = fmaxf(m, __shfl_xor(m, off));
        if (lane == 0) rA[wid] = m;
        __syncthreads();
        m = fmaxf(rA[0], rA[1]);
        float den = 0.f;
        for (int i = tid; i < deg; i += 128) {
            float e = s2[csr[r0 + i]] + dn; e = (e >= 0.f) ? e : 0.2f * e;
            den += __expf(e - m);
        }
        #pragma unroll
        for (int off = 32; off; off >>= 1) den += __shfl_xor(den, off);
        if (lane == 0) rB[wid] = den;
        __syncthreads();
        den = rB[0] + rB[1];
        float inv = 1.f / den;
        for (int c0 = 0; c0 < deg; c0 += 128) {
            __syncthreads();
            int i = c0 + tid;
            if (i < deg) {
                int src = csr[r0 + i];
                src_sh[tid] = src;
                float e = s2[src] + dn; e = (e >= 0.f) ? e : 0.2f * e;
                alpha_sh[tid] = __expf(e - m) * inv;
            }
            __syncthreads();
            gather(min(128, deg - c0));
        }
    }
    // cross-group reduce (conflict-free split halves) + epilogue
    *reinterpret_cast<float4*>(&red[grp][l16 * 4]) =
        make_float4(acc[0], acc[1], acc[2], acc[3]);
    *reinterpret_cast<float4*>(&red[grp][64 + l16 * 4]) =
        make_float4(acc[4], acc[5], acc[6], acc[7]);
    __syncthreads();
    {
        int pos = tid;
        int ch = (pos < 64) ? ((pos >> 2) * 8 + (pos & 3))
                            : (((pos - 64) >> 2) * 8 + 4 + (pos & 3));
        float s = red[0][pos] + red[1][pos] + red[2][pos] + red[3][pos]
                + red[4][pos] + red[5][pos] + red[6][pos] + red[7][pos] + b2[ch];
        s = (s > 0.f) ? s : expm1f(s);
        h2act[(size_t)n * F2 + ch] = s;
    }
}

// ---------------- per-graph max-pool (batch sorted -> contiguous ranges) ----------------
__global__ void graph_pool(const float* __restrict__ h2act, const int* __restrict__ batch,
                           float* __restrict__ out) {
    int gph = blockIdx.x;                     // 64 blocks
    int tid = threadIdx.x;                    // 256: noff = tid>>7, ch = tid&127
    __shared__ int se[2];
    __shared__ float red[128];
    if (tid < 2) {
        int target = gph + tid;               // first index with batch[i] >= target
        int lo = 0, hi = N_NODES;
        while (lo < hi) { int mid = (lo + hi) >> 1; if (batch[mid] < target) lo = mid + 1; else hi = mid; }
        se[tid] = lo;
    }
    __syncthreads();
    int start = se[0], end = se[1];
    int ch = tid & 127, noff = tid >> 7;
    float m = -INFINITY;
    for (int i = start + noff; i < end; i += 2)
        m = fmaxf(m, h2act[(size_t)i * F2 + ch]);
    if (noff == 1) red[ch] = m;
    __syncthreads();
    if (noff == 0) out[gph * F2 + ch] = fmaxf(m, red[ch]);
}

// ---------------- launcher ----------------
extern "C" void kernel_launch(void* const* d_in, const int* in_sizes, int n_in,
                              void* d_out, int out_size, void* d_ws, size_t ws_size,
                              hipStream_t stream) {
    const float* x_scalar = (const float*)d_in[0];
    const int*   x_opcode = (const int*)d_in[1];
    const int*   x_source = (const int*)d_in[2];
    const int*   x_sink   = (const int*)d_in[3];
    const int*   x_string = (const int*)d_in[4];
    const int*   x_payload= (const int*)d_in[5];
    const int*   edge_idx = (const int*)d_in[6];
    const int*   batch    = (const int*)d_in[7];
    const float* emb_op   = (const float*)d_in[8];
    const float* emb_src  = (const float*)d_in[9];
    const float* emb_snk  = (const float*)d_in[10];
    const float* emb_str  = (const float*)d_in[11];
    const float* emb_pay  = (const float*)d_in[12];
    const float* ln_scale = (const float*)d_in[13];
    const float* ln_bias  = (const float*)d_in[14];
    const float* W1       = (const float*)d_in[15];
    const float* att_src1 = (const float*)d_in[16];
    const float* att_dst1 = (const float*)d_in[17];
    const float* b1       = (const float*)d_in[18];
    const float* W2       = (const float*)d_in[19];
    const float* att_src2 = (const float*)d_in[20];
    const float* att_dst2 = (const float*)d_in[21];
    const float* b2       = (const float*)d_in[22];
    float* out = (float*)d_out;

    // workspace layout
    unsigned short* x0  = (unsigned short*)d_ws;               // M_PAD*224 bf16
    unsigned short* h1  = x0 + (size_t)M_PAD * TOT;            // M_PAD*512
    unsigned short* x1  = h1 + (size_t)M_PAD * F1;             // M_PAD*512
    unsigned short* h2  = x1 + (size_t)M_PAD * F1;             // M_PAD*128
    unsigned short* W1T = h2 + (size_t)M_PAD * F2;             // 512*224
    unsigned short* W2T = W1T + (size_t)F1 * TOT;              // 128*512
    float* s1 = (float*)(W2T + (size_t)F2 * F1);               // N*4
    float* d1 = s1 + (size_t)N_NODES * H1;
    float* s2 = d1 + (size_t)N_NODES * H1;                     // N
    float* d2 = s2 + N_NODES;
    int* rowptr = (int*)(d2 + N_NODES);                        // N+1
    int* cursor = rowptr + (N_NODES + 1);                      // N+1
    int* csr    = cursor + (N_NODES + 1);                      // E_TOT
    float* h2act = (float*)x1;                                 // alias: x1 dead after gemm2

    // CSR build
    init_deg<<<(N_NODES + 255) / 256, 256, 0, stream>>>(cursor);
    add_deg<<<(N_EDGES + 255) / 256, 256, 0, stream>>>(edge_idx, cursor);
    scan_deg<<<1, 1024, 0, stream>>>(cursor, rowptr, cursor);
    scatter_edges<<<(E_TOT + 255) / 256, 256, 0, stream>>>(edge_idx, cursor, csr);

    // weight transposes
    transpose_cast<<<(TOT * F1 + 255) / 256, 256, 0, stream>>>(W1, W1T, TOT, F1);
    transpose_cast<<<(F1 * F2 + 255) / 256, 256, 0, stream>>>(W2, W2T, F1, F2);

    // features + LN
    feat_ln<<<(N_NODES + 3) / 4, 256, 0, stream>>>(x_scalar, x_opcode, x_source, x_sink,
                                                   x_string, x_payload, emb_op, emb_src,
                                                   emb_snk, emb_str, emb_pay, ln_scale,
                                                   ln_bias, x0);

    // layer 1
    dim3 g1(M_PAD / 64, F1 / 64);
    gemm_bf16<<<g1, 256, 0, stream>>>(x0, W1T, h1, N_NODES, F1, TOT);
    att_prep1<<<(N_NODES + 3) / 4, 256, 0, stream>>>(h1, att_src1, att_dst1, s1, d1);
    gat1_aggregate<<<N_NODES, 256, 0, stream>>>(h1, s1, d1, rowptr, csr, b1, x1);

    // layer 2
    dim3 g2(M_PAD / 64, F2 / 64);
    gemm_bf16<<<g2, 256, 0, stream>>>(x1, W2T, h2, N_NODES, F2, F1);
    att_prep2<<<(N_NODES + 3) / 4, 256, 0, stream>>>(h2, att_src2, att_dst2, s2, d2);

    gat2_node<<<N_NODES, 128, 0, stream>>>(h2, s2, d2, rowptr, csr, b2, h2act);
    graph_pool<<<N_GRAPH, 256, 0, stream>>>(h2act, batch, out);
}